// Round 1
// baseline (22737.914 us; speedup 1.0000x reference)
//
#include <hip/hip_runtime.h>
#include <hip/hip_bf16.h>
#include <math.h>

// ---- problem constants ----
constexpr int L_   = 2;
constexpr int D_   = 1024;
constexpr int HID_ = 4096;
constexpr int QH_  = 16;
constexpr int KVH_ = 4;
constexpr int V_   = 32000;
constexpr int B_   = 2;
constexpr int S_   = 2048;
constexpr int R_   = 20;
constexpr int HEAD_ = D_ / QH_;   // 64
constexpr int G_    = QH_ / KVH_; // 4
constexpr int KD_   = KVH_ * HEAD_; // 256
constexpr int M_    = B_ * S_;    // 4096 tokens
constexpr float INV_ALPHA_ = 1.0f / 32.0f;
// ln(50000)/32  (freq_i = exp(-i * ln(theta)/(HEAD/2)))
constexpr float LOG_STEP_ = 0.3381180865f;

// ---------------- embedding gather ----------------
__global__ __launch_bounds__(256) void k_embed(const int* __restrict__ xs,
                                               const float* __restrict__ emb,
                                               float* __restrict__ x) {
  int i = blockIdx.x * blockDim.x + threadIdx.x;   // float4 index
  int total4 = M_ * D_ / 4;
  if (i >= total4) return;
  int row = i >> 8;          // D/4 = 256 float4 per row
  int c4  = i & 255;
  const float4* src = reinterpret_cast<const float4*>(emb + (size_t)xs[row] * D_) + c4;
  reinterpret_cast<float4*>(x)[i] = *src;
}

// ---------------- RMSNorm (one block per row) ----------------
__global__ __launch_bounds__(256) void k_rms(const float* __restrict__ x,
                                             const float* __restrict__ scale,
                                             float* __restrict__ out) {
  int row = blockIdx.x;
  const float* xr = x + (size_t)row * D_;
  float ss = 0.f;
  for (int i = threadIdx.x; i < D_; i += 256) { float v = xr[i]; ss += v * v; }
  // wave64 reduce
  for (int off = 32; off > 0; off >>= 1) ss += __shfl_down(ss, off);
  __shared__ float red[5];
  if ((threadIdx.x & 63) == 0) red[threadIdx.x >> 6] = ss;
  __syncthreads();
  if (threadIdx.x == 0)
    red[4] = rsqrtf((red[0] + red[1] + red[2] + red[3]) * (1.0f / D_) + 1e-5f);
  __syncthreads();
  float inv = red[4];
  float* orow = out + (size_t)row * D_;
  for (int i = threadIdx.x; i < D_; i += 256) orow[i] = scale[i] * xr[i] * inv;
}

// ---------------- RoPE (interleaved pairs) ----------------
__global__ __launch_bounds__(256) void k_rope(float* __restrict__ t, int heads, int npairs) {
  int i = blockIdx.x * blockDim.x + threadIdx.x;
  if (i >= npairs) return;
  int pi = i & 31;                 // pair index within head (HEAD/2 = 32)
  int h  = (i >> 5) % heads;
  int r  = i / (32 * heads);       // token index
  int s  = r & (S_ - 1);           // position (startpos == 0)
  float freq = expf(-LOG_STEP_ * (float)pi);
  float ang = (float)s * freq;
  float sn, cs;
  sincosf(ang, &sn, &cs);
  size_t base = ((size_t)r * heads + h) * HEAD_ + 2 * pi;
  float t0 = t[base], t1 = t[base + 1];
  t[base]     = t0 * cs - t1 * sn;
  t[base + 1] = t0 * sn + t1 * cs;
}

// ---------------- flash attention, one wave per (b, qh, sq) row ----------------
// reads q row from qo, writes output row back to qo (in place)
__global__ __launch_bounds__(64) void k_attn(float* __restrict__ qo,
                                             const float* __restrict__ k,
                                             const float* __restrict__ v) {
  int bid = blockIdx.x;
  int sq = bid & (S_ - 1);
  int qh = (bid >> 11) & (QH_ - 1);
  int b  = bid >> 15;
  int lane = threadIdx.x;
  int kh = qh >> 2;   // qh = kh*G + g
  size_t qoff = ((size_t)(b * S_ + sq) * D_) + qh * HEAD_ + lane;
  float qd = qo[qoff] * 0.125f;   // 1/sqrt(64)
  const float* kbase = k + (size_t)b * S_ * KD_ + kh * HEAD_ + lane;
  const float* vbase = v + (size_t)b * S_ * KD_ + kh * HEAD_ + lane;
  float m = -INFINITY, l = 0.f, acc = 0.f;
  for (int t = 0; t <= sq; ++t) {
    float s = qd * kbase[(size_t)t * KD_];
    for (int off = 32; off > 0; off >>= 1) s += __shfl_xor(s, off);
    float mn = fmaxf(m, s);
    float corr = expf(m - mn);     // first iter: exp(-inf) = 0
    float p = expf(s - mn);
    l = l * corr + p;
    acc = acc * corr + p * vbase[(size_t)t * KD_];
    m = mn;
  }
  qo[qoff] = acc / l;
}

// ---------------- SiLU-mul: g1 = g1 * silu(g2) ----------------
__global__ __launch_bounds__(256) void k_silumul(float* __restrict__ g1,
                                                 const float* __restrict__ g2, int n) {
  int i = blockIdx.x * blockDim.x + threadIdx.x;
  if (i >= n) return;
  float a = g1[i], b = g2[i];
  g1[i] = a * b / (1.f + __expf(-b));
}

// ---------------- guarded tiled f32 GEMM ----------------
// C[M,N] = alpha * (A[M,K] @ B + bias[N]) + beta * Cin[M,N]
// BT=false: B is [K,N] row-major.  BT=true: B is [N,K] row-major (i.e. B^T).
template <bool BT>
__global__ __launch_bounds__(256) void k_gemm(const float* __restrict__ A,
                                              const float* __restrict__ B,
                                              const float* __restrict__ bias,
                                              const float* __restrict__ Cin,
                                              float* __restrict__ C,
                                              int M, int N, int K,
                                              float alpha, float beta) {
  constexpr int BM = 128, BN = 128, BK = 8;
  __shared__ float As[BK][BM];
  __shared__ float Bs[BK][BN];
  const int tid = threadIdx.x;
  const int bm = blockIdx.y * BM;
  const int bn = blockIdx.x * BN;
  const int tx = tid & 15;   // col group
  const int ty = tid >> 4;   // row group
  float acc[8][8];
#pragma unroll
  for (int i = 0; i < 8; ++i)
#pragma unroll
    for (int j = 0; j < 8; ++j) acc[i][j] = 0.f;

  for (int k0 = 0; k0 < K; k0 += BK) {
    { // A tile -> As[k][m]
      const int r = tid >> 1;
      const int c = (tid & 1) * 4;
      float v0 = 0, v1 = 0, v2 = 0, v3 = 0;
      const int gr = bm + r;
      if (gr < M) {
        const float* p = A + (size_t)gr * K + k0 + c;
        if (k0 + c + 3 < K) {
          float4 t4 = *reinterpret_cast<const float4*>(p);
          v0 = t4.x; v1 = t4.y; v2 = t4.z; v3 = t4.w;
        } else {
          if (k0 + c + 0 < K) v0 = p[0];
          if (k0 + c + 1 < K) v1 = p[1];
          if (k0 + c + 2 < K) v2 = p[2];
          if (k0 + c + 3 < K) v3 = p[3];
        }
      }
      As[c + 0][r] = v0; As[c + 1][r] = v1; As[c + 2][r] = v2; As[c + 3][r] = v3;
    }
    if (!BT) { // B tile [K,N] -> Bs[k][n]
      const int r = tid >> 5;          // k
      const int c = (tid & 31) * 4;    // n
      float v0 = 0, v1 = 0, v2 = 0, v3 = 0;
      const int gk = k0 + r;
      if (gk < K) {
        const float* p = B + (size_t)gk * N + bn + c;
        if (bn + c + 3 < N) {
          float4 t4 = *reinterpret_cast<const float4*>(p);
          v0 = t4.x; v1 = t4.y; v2 = t4.z; v3 = t4.w;
        } else {
          if (bn + c + 0 < N) v0 = p[0];
          if (bn + c + 1 < N) v1 = p[1];
          if (bn + c + 2 < N) v2 = p[2];
          if (bn + c + 3 < N) v3 = p[3];
        }
      }
      Bs[r][c + 0] = v0; Bs[r][c + 1] = v1; Bs[r][c + 2] = v2; Bs[r][c + 3] = v3;
    } else { // B tile from B^T [N,K] -> Bs[k][n]
      const int r = tid >> 1;          // n
      const int c = (tid & 1) * 4;     // k
      float v0 = 0, v1 = 0, v2 = 0, v3 = 0;
      const int gn = bn + r;
      if (gn < N) {
        const float* p = B + (size_t)gn * K + k0 + c;
        if (k0 + c + 3 < K) {
          float4 t4 = *reinterpret_cast<const float4*>(p);
          v0 = t4.x; v1 = t4.y; v2 = t4.z; v3 = t4.w;
        } else {
          if (k0 + c + 0 < K) v0 = p[0];
          if (k0 + c + 1 < K) v1 = p[1];
          if (k0 + c + 2 < K) v2 = p[2];
          if (k0 + c + 3 < K) v3 = p[3];
        }
      }
      Bs[c + 0][r] = v0; Bs[c + 1][r] = v1; Bs[c + 2][r] = v2; Bs[c + 3][r] = v3;
    }
    __syncthreads();
#pragma unroll
    for (int kk = 0; kk < BK; ++kk) {
      float a[8], b[8];
      float4 a0 = *reinterpret_cast<const float4*>(&As[kk][ty * 8]);
      float4 a1 = *reinterpret_cast<const float4*>(&As[kk][ty * 8 + 4]);
      float4 b0 = *reinterpret_cast<const float4*>(&Bs[kk][tx * 8]);
      float4 b1 = *reinterpret_cast<const float4*>(&Bs[kk][tx * 8 + 4]);
      a[0] = a0.x; a[1] = a0.y; a[2] = a0.z; a[3] = a0.w;
      a[4] = a1.x; a[5] = a1.y; a[6] = a1.z; a[7] = a1.w;
      b[0] = b0.x; b[1] = b0.y; b[2] = b0.z; b[3] = b0.w;
      b[4] = b1.x; b[5] = b1.y; b[6] = b1.z; b[7] = b1.w;
#pragma unroll
      for (int i = 0; i < 8; ++i)
#pragma unroll
        for (int j = 0; j < 8; ++j) acc[i][j] = fmaf(a[i], b[j], acc[i][j]);
    }
    __syncthreads();
  }
#pragma unroll
  for (int i = 0; i < 8; ++i) {
    const int row = bm + ty * 8 + i;
    if (row >= M) continue;
#pragma unroll
    for (int j = 0; j < 8; ++j) {
      const int col = bn + tx * 8 + j;
      if (col >= N) continue;
      float vv = acc[i][j];
      if (bias) vv += bias[col];
      vv *= alpha;
      if (beta != 0.f) vv += beta * Cin[(size_t)row * N + col];
      C[(size_t)row * N + col] = vv;
    }
  }
}

static inline void gemm_nn(hipStream_t st, const float* A, const float* B,
                           const float* bias, const float* Cin, float* C,
                           int M, int N, int K, float alpha, float beta) {
  dim3 g((N + 127) / 128, (M + 127) / 128);
  k_gemm<false><<<g, 256, 0, st>>>(A, B, bias, Cin, C, M, N, K, alpha, beta);
}
static inline void gemm_nt(hipStream_t st, const float* A, const float* Bt,
                           const float* bias, const float* Cin, float* C,
                           int M, int N, int K, float alpha, float beta) {
  dim3 g((N + 127) / 128, (M + 127) / 128);
  k_gemm<true><<<g, 256, 0, st>>>(A, Bt, bias, Cin, C, M, N, K, alpha, beta);
}

extern "C" void kernel_launch(void* const* d_in, const int* in_sizes, int n_in,
                              void* d_out, int out_size, void* d_ws, size_t ws_size,
                              hipStream_t stream) {
  (void)in_sizes; (void)n_in; (void)out_size; (void)ws_size;
  const int*   xs  = (const int*)d_in[0];
  const float* emb = (const float*)d_in[1];
  const float* Wq  = (const float*)d_in[2];
  const float* bq  = (const float*)d_in[3];
  const float* Wk  = (const float*)d_in[4];
  const float* bk  = (const float*)d_in[5];
  const float* Wv  = (const float*)d_in[6];
  const float* bv  = (const float*)d_in[7];
  const float* Wo  = (const float*)d_in[8];
  const float* bo  = (const float*)d_in[9];
  const float* att_scale   = (const float*)d_in[10];
  const float* mlp_scale   = (const float*)d_in[11];
  const float* final_scale = (const float*)d_in[12];
  const float* W1  = (const float*)d_in[13];
  const float* A1  = (const float*)d_in[14];
  const float* a1b = (const float*)d_in[15];
  const float* B1  = (const float*)d_in[16];
  const float* b1b = (const float*)d_in[17];
  const float* W2  = (const float*)d_in[18];
  const float* A2  = (const float*)d_in[19];
  const float* a2b = (const float*)d_in[20];
  const float* B2  = (const float*)d_in[21];
  const float* b2b = (const float*)d_in[22];
  const float* W3  = (const float*)d_in[23];
  const float* A3  = (const float*)d_in[24];
  const float* a3b = (const float*)d_in[25];
  const float* B3  = (const float*)d_in[26];
  const float* b3b = (const float*)d_in[27];
  // d_in[28] = startpos, always 0 in this problem (assumed; causal mask applied)
  float* out = (float*)d_out;

  // workspace layout (f32): ~184 MiB total
  float* ws   = (float*)d_ws;
  float* xbuf = ws;                           // M*D
  float* hbuf = xbuf + (size_t)M_ * D_;       // M*D
  float* qbuf = hbuf + (size_t)M_ * D_;       // M*D   (q, then attn out in place)
  float* kbuf = qbuf + (size_t)M_ * D_;       // M*KD
  float* vbuf = kbuf + (size_t)M_ * KD_;      // M*KD
  float* g1   = vbuf + (size_t)M_ * KD_;      // M*HID
  float* g2   = g1 + (size_t)M_ * HID_;       // M*HID
  float* ubuf = g2 + (size_t)M_ * HID_;       // M*R

  // embedding gather
  k_embed<<<dim3(M_ * D_ / 4 / 256), dim3(256), 0, stream>>>(xs, emb, xbuf);

  for (int l = 0; l < L_; ++l) {
    // ---- attention block ----
    k_rms<<<dim3(M_), dim3(256), 0, stream>>>(xbuf, att_scale + (size_t)l * D_, hbuf);
    gemm_nn(stream, hbuf, Wq + (size_t)l * D_ * D_,  bq + (size_t)l * D_,  nullptr, qbuf, M_, D_,  D_, 1.f, 0.f);
    gemm_nn(stream, hbuf, Wk + (size_t)l * D_ * KD_, bk + (size_t)l * KD_, nullptr, kbuf, M_, KD_, D_, 1.f, 0.f);
    gemm_nn(stream, hbuf, Wv + (size_t)l * D_ * KD_, bv + (size_t)l * KD_, nullptr, vbuf, M_, KD_, D_, 1.f, 0.f);
    {
      int npq = M_ * QH_ * 32;
      k_rope<<<dim3(npq / 256), dim3(256), 0, stream>>>(qbuf, QH_, npq);
      int npk = M_ * KVH_ * 32;
      k_rope<<<dim3(npk / 256), dim3(256), 0, stream>>>(kbuf, KVH_, npk);
    }
    k_attn<<<dim3(B_ * QH_ * S_), dim3(64), 0, stream>>>(qbuf, kbuf, vbuf);
    // x += o @ Wo + bo
    gemm_nn(stream, qbuf, Wo + (size_t)l * D_ * D_, bo + (size_t)l * D_, xbuf, xbuf, M_, D_, D_, 1.f, 1.f);

    // ---- MLP block ----
    k_rms<<<dim3(M_), dim3(256), 0, stream>>>(xbuf, mlp_scale + (size_t)l * D_, hbuf);
    // lora1 -> g1
    gemm_nn(stream, hbuf, W1 + (size_t)l * D_ * HID_, nullptr, nullptr, g1, M_, HID_, D_, 1.f, 0.f);
    gemm_nn(stream, hbuf, A1 + (size_t)l * D_ * R_, a1b + (size_t)l * R_, nullptr, ubuf, M_, R_, D_, 1.f, 0.f);
    gemm_nn(stream, ubuf, B1 + (size_t)l * R_ * HID_, b1b + (size_t)l * HID_, g1, g1, M_, HID_, R_, INV_ALPHA_, 1.f);
    // lora2 -> g2
    gemm_nn(stream, hbuf, W2 + (size_t)l * D_ * HID_, nullptr, nullptr, g2, M_, HID_, D_, 1.f, 0.f);
    gemm_nn(stream, hbuf, A2 + (size_t)l * D_ * R_, a2b + (size_t)l * R_, nullptr, ubuf, M_, R_, D_, 1.f, 0.f);
    gemm_nn(stream, ubuf, B2 + (size_t)l * R_ * HID_, b2b + (size_t)l * HID_, g2, g2, M_, HID_, R_, INV_ALPHA_, 1.f);
    // m = g1 * silu(g2)
    k_silumul<<<dim3(M_ * HID_ / 256), dim3(256), 0, stream>>>(g1, g2, M_ * HID_);
    // x += lora3(m)
    gemm_nn(stream, g1, W3 + (size_t)l * HID_ * D_, nullptr, xbuf, xbuf, M_, D_, HID_, 1.f, 1.f);
    gemm_nn(stream, g1, A3 + (size_t)l * HID_ * R_, a3b + (size_t)l * R_, nullptr, ubuf, M_, R_, HID_, 1.f, 0.f);
    gemm_nn(stream, ubuf, B3 + (size_t)l * R_ * D_, b3b + (size_t)l * D_, xbuf, xbuf, M_, D_, R_, INV_ALPHA_, 1.f);
  }

  // final norm + vocab projection: out = rms(x, final_scale) @ emb^T
  k_rms<<<dim3(M_), dim3(256), 0, stream>>>(xbuf, final_scale, hbuf);
  gemm_nt(stream, hbuf, emb, nullptr, nullptr, out, M_, V_, D_, 1.f, 0.f);
}

// Round 2
// 7002.767 us; speedup vs baseline: 3.2470x; 3.2470x over previous
//
#include <hip/hip_runtime.h>
#include <hip/hip_bf16.h>
#include <math.h>

// ---- problem constants ----
constexpr int L_   = 2;
constexpr int D_   = 1024;
constexpr int HID_ = 4096;
constexpr int QH_  = 16;
constexpr int KVH_ = 4;
constexpr int V_   = 32000;
constexpr int B_   = 2;
constexpr int S_   = 2048;
constexpr int R_   = 20;
constexpr int HEAD_ = D_ / QH_;   // 64
constexpr int KD_   = KVH_ * HEAD_; // 256
constexpr int M_    = B_ * S_;    // 4096 tokens
constexpr float INV_ALPHA_ = 1.0f / 32.0f;
constexpr float LOG_STEP_ = 0.3381180865f;  // ln(50000)/32

typedef unsigned short ushort_t;
typedef __attribute__((ext_vector_type(8))) short bf16x8;
typedef __attribute__((ext_vector_type(4))) float f32x4;
typedef __attribute__((address_space(1))) const unsigned int gas_u32;
typedef __attribute__((address_space(3))) unsigned int las_u32;

__device__ __forceinline__ void gload16(const void* g, void* l) {
  __builtin_amdgcn_global_load_lds((gas_u32*)g, (las_u32*)l, 16, 0, 0);
}

__device__ __forceinline__ ushort_t f2bf(float f) {
  union { float f; unsigned int u; } c; c.f = f;
  unsigned int u = c.u + 0x7FFFu + ((c.u >> 16) & 1u);  // RNE
  return (ushort_t)(u >> 16);
}

// ---------------- embedding gather ----------------
__global__ __launch_bounds__(256) void k_embed(const int* __restrict__ xs,
                                               const float* __restrict__ emb,
                                               float* __restrict__ x) {
  int i = blockIdx.x * blockDim.x + threadIdx.x;
  int total4 = M_ * D_ / 4;
  if (i >= total4) return;
  int row = i >> 8;
  int c4  = i & 255;
  const float4* src = reinterpret_cast<const float4*>(emb + (size_t)xs[row] * D_) + c4;
  reinterpret_cast<float4*>(x)[i] = *src;
}

// ---------------- RMSNorm ----------------
__global__ __launch_bounds__(256) void k_rms(const float* __restrict__ x,
                                             const float* __restrict__ scale,
                                             float* __restrict__ out) {
  int row = blockIdx.x;
  const float* xr = x + (size_t)row * D_;
  float ss = 0.f;
  for (int i = threadIdx.x; i < D_; i += 256) { float v = xr[i]; ss += v * v; }
  for (int off = 32; off > 0; off >>= 1) ss += __shfl_down(ss, off);
  __shared__ float red[5];
  if ((threadIdx.x & 63) == 0) red[threadIdx.x >> 6] = ss;
  __syncthreads();
  if (threadIdx.x == 0)
    red[4] = rsqrtf((red[0] + red[1] + red[2] + red[3]) * (1.0f / D_) + 1e-5f);
  __syncthreads();
  float inv = red[4];
  float* orow = out + (size_t)row * D_;
  for (int i = threadIdx.x; i < D_; i += 256) orow[i] = scale[i] * xr[i] * inv;
}

// ---------------- casts ----------------
__global__ __launch_bounds__(256) void k_cast(const float* __restrict__ in,
                                              ushort_t* __restrict__ out, int n8) {
  int i = blockIdx.x * blockDim.x + threadIdx.x;
  if (i >= n8) return;
  const float4* p = reinterpret_cast<const float4*>(in) + i * 2;
  float4 a = p[0], b = p[1];
  ushort_t r[8] = { f2bf(a.x), f2bf(a.y), f2bf(a.z), f2bf(a.w),
                    f2bf(b.x), f2bf(b.y), f2bf(b.z), f2bf(b.w) };
  reinterpret_cast<uint4*>(out)[i] = *reinterpret_cast<uint4*>(r);
}

// transpose+cast: in f32 [K][N] -> out bf16 [N][K]
__global__ __launch_bounds__(256) void k_tcast(const float* __restrict__ in,
                                               ushort_t* __restrict__ out,
                                               int K, int N) {
  __shared__ float t[32][33];
  int n0 = blockIdx.x * 32, k0 = blockIdx.y * 32;
  int c = threadIdx.x & 31, r0 = threadIdx.x >> 5;
#pragma unroll
  for (int rr = 0; rr < 4; ++rr) {
    int r = r0 + rr * 8;
    t[r][c] = in[(size_t)(k0 + r) * N + n0 + c];
  }
  __syncthreads();
#pragma unroll
  for (int rr = 0; rr < 4; ++rr) {
    int r = r0 + rr * 8;
    out[(size_t)(n0 + r) * K + k0 + c] = f2bf(t[c][r]);
  }
}

// ---------------- RoPE ----------------
__global__ __launch_bounds__(256) void k_rope(float* __restrict__ t, int heads, int npairs) {
  int i = blockIdx.x * blockDim.x + threadIdx.x;
  if (i >= npairs) return;
  int pi = i & 31;
  int h  = (i >> 5) % heads;
  int r  = i / (32 * heads);
  int s  = r & (S_ - 1);
  float freq = expf(-LOG_STEP_ * (float)pi);
  float ang = (float)s * freq;
  float sn, cs;
  sincosf(ang, &sn, &cs);
  size_t base = ((size_t)r * heads + h) * HEAD_ + 2 * pi;
  float t0 = t[base], t1 = t[base + 1];
  t[base]     = t0 * cs - t1 * sn;
  t[base + 1] = t0 * sn + t1 * cs;
}

// ---------------- tiled flash attention ----------------
// block = 4 waves = 4 consecutive q rows of one (b, qh); 64-key tiles in LDS.
__device__ __forceinline__ float wredmax(float x) {
#pragma unroll
  for (int o = 1; o < 64; o <<= 1) x = fmaxf(x, __shfl_xor(x, o));
  return x;
}
__device__ __forceinline__ float wredsum(float x) {
#pragma unroll
  for (int o = 1; o < 64; o <<= 1) x += __shfl_xor(x, o);
  return x;
}

__global__ __launch_bounds__(256) void k_attn2(float* __restrict__ qo,
                                               const float* __restrict__ k,
                                               const float* __restrict__ v) {
  __shared__ float KT[64 * 65];   // [d][key], pad 65
  __shared__ float Vs[64 * 64];   // [key][d]
  __shared__ float qsh[4][64];
  __shared__ float psh[4][64];

  int t = blockIdx.x;
  int sq0 = (t & 511) * 4;
  int qh  = (t >> 9) & 15;
  int b   = t >> 13;
  int tid = threadIdx.x;
  int w = tid >> 6, lane = tid & 63;
  int sq = sq0 + w;
  int kh = qh >> 2;

  size_t qoff = ((size_t)(b * S_ + sq) * D_) + qh * HEAD_ + lane;
  qsh[w][lane] = qo[qoff] * 0.125f;
  __syncthreads();

  const float* kbase = k + (size_t)b * S_ * KD_ + kh * HEAD_;
  const float4* v4 = reinterpret_cast<const float4*>(v + (size_t)b * S_ * KD_ + kh * HEAD_);

  float m = -INFINITY, lsum = 0.f, acc = 0.f;

  for (int t0 = 0; t0 <= sq0; t0 += 64) {
    // stage K^T (transposed, padded) and V
#pragma unroll
    for (int r = 0; r < 16; ++r) {
      int idx = tid + r * 256;
      int key = idx >> 6, d = idx & 63;
      KT[d * 65 + key] = kbase[(size_t)(t0 + key) * KD_ + d];
    }
#pragma unroll
    for (int r = 0; r < 4; ++r) {
      int idx = tid + r * 256;
      int key = idx >> 4, d4 = idx & 15;
      reinterpret_cast<float4*>(Vs)[key * 16 + d4] = v4[(size_t)(t0 + key) * 64 + d4];
    }
    __syncthreads();

    // scores: lane <-> key
    float s0 = 0.f, s1 = 0.f, s2 = 0.f, s3 = 0.f;
#pragma unroll
    for (int d = 0; d < 64; d += 4) {
      s0 = fmaf(qsh[w][d + 0], KT[(d + 0) * 65 + lane], s0);
      s1 = fmaf(qsh[w][d + 1], KT[(d + 1) * 65 + lane], s1);
      s2 = fmaf(qsh[w][d + 2], KT[(d + 2) * 65 + lane], s2);
      s3 = fmaf(qsh[w][d + 3], KT[(d + 3) * 65 + lane], s3);
    }
    float s = (s0 + s1) + (s2 + s3);
    bool valid = (t0 + lane) <= sq;
    s = valid ? s : -INFINITY;

    float mt = wredmax(s);
    float mn = fmaxf(m, mt);
    float corr = __expf(m - mn);       // first tile: exp(-inf)=0
    float p = __expf(s - mn);          // invalid -> exp(-inf)=0
    lsum = lsum * corr + wredsum(p);
    psh[w][lane] = p;

    float a0 = 0.f, a1 = 0.f, a2 = 0.f, a3 = 0.f;
#pragma unroll
    for (int j = 0; j < 64; j += 4) {
      a0 = fmaf(psh[w][j + 0], Vs[(j + 0) * 64 + lane], a0);
      a1 = fmaf(psh[w][j + 1], Vs[(j + 1) * 64 + lane], a1);
      a2 = fmaf(psh[w][j + 2], Vs[(j + 2) * 64 + lane], a2);
      a3 = fmaf(psh[w][j + 3], Vs[(j + 3) * 64 + lane], a3);
    }
    acc = acc * corr + ((a0 + a1) + (a2 + a3));
    m = mn;
    __syncthreads();
  }
  qo[qoff] = acc / lsum;
}

// ---------------- SiLU-mul ----------------
__global__ __launch_bounds__(256) void k_silumul(float* __restrict__ g1,
                                                 const float* __restrict__ g2, int n) {
  int i = blockIdx.x * blockDim.x + threadIdx.x;
  if (i >= n) return;
  float a = g1[i], b = g2[i];
  g1[i] = a * b / (1.f + __expf(-b));
}

// ---------------- bf16 MFMA GEMM (m97 structure) ----------------
// C[M,N] = A[M,K]_bf16 @ Bt[N,K]_bf16^T (+bias) (+Cin), f32 out.
// M,N multiples of 128; K multiple of 32. 256 threads, 2x2 waves, 4x4 frags.
__global__ __launch_bounds__(256) void k_bgemm(const ushort_t* __restrict__ A,
                                               const ushort_t* __restrict__ Bt,
                                               const float* __restrict__ bias,
                                               const float* __restrict__ Cin,
                                               float* __restrict__ C,
                                               int M, int N, int K) {
  __shared__ ushort_t As[128 * 32];
  __shared__ ushort_t Bs[128 * 32];
  const int tid = threadIdx.x;
  const int lane = tid & 63;
  const int w = tid >> 6;
  const int wr = w >> 1, wc = w & 1;
  const int bm = blockIdx.y * 128, bn = blockIdx.x * 128;

  f32x4 acc[4][4];
#pragma unroll
  for (int i = 0; i < 4; ++i)
#pragma unroll
    for (int j = 0; j < 4; ++j) acc[i][j] = {0.f, 0.f, 0.f, 0.f};

  const int c0 = w * 2;
  const int srow = (lane >> 2);         // 0..15 within chunk
  const int skcol = (lane & 3) * 8;     // 0,8,16,24

  for (int k0 = 0; k0 < K; k0 += 32) {
#pragma unroll
    for (int q = 0; q < 2; ++q) {
      int c = c0 + q;
      const ushort_t* ga = A + (size_t)(bm + c * 16 + srow) * K + k0 + skcol;
      gload16(ga, (char*)As + c * 1024);
      const ushort_t* gb = Bt + (size_t)(bn + c * 16 + srow) * K + k0 + skcol;
      gload16(gb, (char*)Bs + c * 1024);
    }
    __syncthreads();

    bf16x8 af[4], bf[4];
    const int koff = (lane >> 4) * 8;
    const int rsel = lane & 15;
#pragma unroll
    for (int i = 0; i < 4; ++i)
      af[i] = *reinterpret_cast<const bf16x8*>(&As[(wr * 64 + i * 16 + rsel) * 32 + koff]);
#pragma unroll
    for (int i = 0; i < 4; ++i)
      bf[i] = *reinterpret_cast<const bf16x8*>(&Bs[(wc * 64 + i * 16 + rsel) * 32 + koff]);
#pragma unroll
    for (int i = 0; i < 4; ++i)
#pragma unroll
      for (int j = 0; j < 4; ++j)
        acc[i][j] = __builtin_amdgcn_mfma_f32_16x16x32_bf16(af[i], bf[j], acc[i][j], 0, 0, 0);
    __syncthreads();
  }

  // epilogue
#pragma unroll
  for (int i = 0; i < 4; ++i) {
    int row0 = bm + wr * 64 + i * 16 + (lane >> 4) * 4;
#pragma unroll
    for (int j = 0; j < 4; ++j) {
      int col = bn + wc * 64 + j * 16 + (lane & 15);
      float bv = bias ? bias[col] : 0.f;
#pragma unroll
      for (int e = 0; e < 4; ++e) {
        int row = row0 + e;
        float vv = acc[i][j][e] + bv;
        if (Cin) vv += Cin[(size_t)row * N + col];
        C[(size_t)row * N + col] = vv;
      }
    }
  }
}

// ---------------- guarded tiled f32 GEMM (LoRA only) ----------------
template <bool BT>
__global__ __launch_bounds__(256) void k_gemm(const float* __restrict__ A,
                                              const float* __restrict__ B,
                                              const float* __restrict__ bias,
                                              const float* __restrict__ Cin,
                                              float* __restrict__ C,
                                              int M, int N, int K,
                                              float alpha, float beta) {
  constexpr int BM = 128, BN = 128, BK = 8;
  __shared__ float As[BK][BM];
  __shared__ float Bs[BK][BN];
  const int tid = threadIdx.x;
  const int bm = blockIdx.y * BM;
  const int bn = blockIdx.x * BN;
  const int tx = tid & 15;
  const int ty = tid >> 4;
  float acc[8][8];
#pragma unroll
  for (int i = 0; i < 8; ++i)
#pragma unroll
    for (int j = 0; j < 8; ++j) acc[i][j] = 0.f;

  for (int k0 = 0; k0 < K; k0 += BK) {
    {
      const int r = tid >> 1;
      const int c = (tid & 1) * 4;
      float v0 = 0, v1 = 0, v2 = 0, v3 = 0;
      const int gr = bm + r;
      if (gr < M) {
        const float* p = A + (size_t)gr * K + k0 + c;
        if (k0 + c + 3 < K) {
          float4 t4 = *reinterpret_cast<const float4*>(p);
          v0 = t4.x; v1 = t4.y; v2 = t4.z; v3 = t4.w;
        } else {
          if (k0 + c + 0 < K) v0 = p[0];
          if (k0 + c + 1 < K) v1 = p[1];
          if (k0 + c + 2 < K) v2 = p[2];
          if (k0 + c + 3 < K) v3 = p[3];
        }
      }
      As[c + 0][r] = v0; As[c + 1][r] = v1; As[c + 2][r] = v2; As[c + 3][r] = v3;
    }
    if (!BT) {
      const int r = tid >> 5;
      const int c = (tid & 31) * 4;
      float v0 = 0, v1 = 0, v2 = 0, v3 = 0;
      const int gk = k0 + r;
      if (gk < K) {
        const float* p = B + (size_t)gk * N + bn + c;
        if (bn + c + 3 < N) {
          float4 t4 = *reinterpret_cast<const float4*>(p);
          v0 = t4.x; v1 = t4.y; v2 = t4.z; v3 = t4.w;
        } else {
          if (bn + c + 0 < N) v0 = p[0];
          if (bn + c + 1 < N) v1 = p[1];
          if (bn + c + 2 < N) v2 = p[2];
          if (bn + c + 3 < N) v3 = p[3];
        }
      }
      Bs[r][c + 0] = v0; Bs[r][c + 1] = v1; Bs[r][c + 2] = v2; Bs[r][c + 3] = v3;
    } else {
      const int r = tid >> 1;
      const int c = (tid & 1) * 4;
      float v0 = 0, v1 = 0, v2 = 0, v3 = 0;
      const int gn = bn + r;
      if (gn < N) {
        const float* p = B + (size_t)gn * K + k0 + c;
        if (k0 + c + 3 < K) {
          float4 t4 = *reinterpret_cast<const float4*>(p);
          v0 = t4.x; v1 = t4.y; v2 = t4.z; v3 = t4.w;
        } else {
          if (k0 + c + 0 < K) v0 = p[0];
          if (k0 + c + 1 < K) v1 = p[1];
          if (k0 + c + 2 < K) v2 = p[2];
          if (k0 + c + 3 < K) v3 = p[3];
        }
      }
      Bs[c + 0][r] = v0; Bs[c + 1][r] = v1; Bs[c + 2][r] = v2; Bs[c + 3][r] = v3;
    }
    __syncthreads();
#pragma unroll
    for (int kk = 0; kk < BK; ++kk) {
      float a[8], b[8];
      float4 a0 = *reinterpret_cast<const float4*>(&As[kk][ty * 8]);
      float4 a1 = *reinterpret_cast<const float4*>(&As[kk][ty * 8 + 4]);
      float4 b0 = *reinterpret_cast<const float4*>(&Bs[kk][tx * 8]);
      float4 b1 = *reinterpret_cast<const float4*>(&Bs[kk][tx * 8 + 4]);
      a[0] = a0.x; a[1] = a0.y; a[2] = a0.z; a[3] = a0.w;
      a[4] = a1.x; a[5] = a1.y; a[6] = a1.z; a[7] = a1.w;
      b[0] = b0.x; b[1] = b0.y; b[2] = b0.z; b[3] = b0.w;
      b[4] = b1.x; b[5] = b1.y; b[6] = b1.z; b[7] = b1.w;
#pragma unroll
      for (int i = 0; i < 8; ++i)
#pragma unroll
        for (int j = 0; j < 8; ++j) acc[i][j] = fmaf(a[i], b[j], acc[i][j]);
    }
    __syncthreads();
  }
#pragma unroll
  for (int i = 0; i < 8; ++i) {
    const int row = bm + ty * 8 + i;
    if (row >= M) continue;
#pragma unroll
    for (int j = 0; j < 8; ++j) {
      const int col = bn + tx * 8 + j;
      if (col >= N) continue;
      float vv = acc[i][j];
      if (bias) vv += bias[col];
      vv *= alpha;
      if (beta != 0.f) vv += beta * Cin[(size_t)row * N + col];
      C[(size_t)row * N + col] = vv;
    }
  }
}

static inline void gemm_nn(hipStream_t st, const float* A, const float* B,
                           const float* bias, const float* Cin, float* C,
                           int M, int N, int K, float alpha, float beta) {
  dim3 g((N + 127) / 128, (M + 127) / 128);
  k_gemm<false><<<g, 256, 0, st>>>(A, B, bias, Cin, C, M, N, K, alpha, beta);
}

static inline void bgemm(hipStream_t st, const ushort_t* A, const ushort_t* Bt,
                         const float* bias, const float* Cin, float* C,
                         int M, int N, int K) {
  dim3 g(N / 128, M / 128);
  k_bgemm<<<g, 256, 0, st>>>(A, Bt, bias, Cin, C, M, N, K);
}

static inline void tcast(hipStream_t st, const float* in, ushort_t* out, int K, int N) {
  dim3 g(N / 32, K / 32);
  k_tcast<<<g, 256, 0, st>>>(in, out, K, N);
}

static inline void cast_bf16(hipStream_t st, const float* in, ushort_t* out, size_t n) {
  int n8 = (int)(n / 8);
  k_cast<<<(n8 + 255) / 256, 256, 0, st>>>(in, out, n8);
}

extern "C" void kernel_launch(void* const* d_in, const int* in_sizes, int n_in,
                              void* d_out, int out_size, void* d_ws, size_t ws_size,
                              hipStream_t stream) {
  (void)in_sizes; (void)n_in; (void)out_size; (void)ws_size;
  const int*   xs  = (const int*)d_in[0];
  const float* emb = (const float*)d_in[1];
  const float* Wq  = (const float*)d_in[2];
  const float* bq  = (const float*)d_in[3];
  const float* Wk  = (const float*)d_in[4];
  const float* bk  = (const float*)d_in[5];
  const float* Wv  = (const float*)d_in[6];
  const float* bv  = (const float*)d_in[7];
  const float* Wo  = (const float*)d_in[8];
  const float* bo  = (const float*)d_in[9];
  const float* att_scale   = (const float*)d_in[10];
  const float* mlp_scale   = (const float*)d_in[11];
  const float* final_scale = (const float*)d_in[12];
  const float* W1  = (const float*)d_in[13];
  const float* A1  = (const float*)d_in[14];
  const float* a1b = (const float*)d_in[15];
  const float* B1  = (const float*)d_in[16];
  const float* b1b = (const float*)d_in[17];
  const float* W2  = (const float*)d_in[18];
  const float* A2  = (const float*)d_in[19];
  const float* a2b = (const float*)d_in[20];
  const float* B2  = (const float*)d_in[21];
  const float* b2b = (const float*)d_in[22];
  const float* W3  = (const float*)d_in[23];
  const float* A3  = (const float*)d_in[24];
  const float* a3b = (const float*)d_in[25];
  const float* B3  = (const float*)d_in[26];
  const float* b3b = (const float*)d_in[27];
  float* out = (float*)d_out;

  // f32 workspace
  float* ws   = (float*)d_ws;
  float* xbuf = ws;
  float* hbuf = xbuf + (size_t)M_ * D_;
  float* qbuf = hbuf + (size_t)M_ * D_;
  float* kbuf = qbuf + (size_t)M_ * D_;
  float* vbuf = kbuf + (size_t)M_ * KD_;
  float* g1   = vbuf + (size_t)M_ * KD_;
  float* g2   = g1 + (size_t)M_ * HID_;
  float* ubuf = g2 + (size_t)M_ * HID_;
  // bf16 scratch
  ushort_t* hb   = (ushort_t*)(ubuf + (size_t)M_ * R_);   // up to M*HID
  ushort_t* wT   = hb + (size_t)M_ * HID_;                // up to HID*D
  ushort_t* embT = (ushort_t*)g2;                          // alias (final only)

  k_embed<<<dim3(M_ * D_ / 4 / 256), dim3(256), 0, stream>>>(xs, emb, xbuf);

  for (int l = 0; l < L_; ++l) {
    // ---- attention ----
    k_rms<<<dim3(M_), dim3(256), 0, stream>>>(xbuf, att_scale + (size_t)l * D_, hbuf);
    cast_bf16(stream, hbuf, hb, (size_t)M_ * D_);
    tcast(stream, Wq + (size_t)l * D_ * D_, wT, D_, D_);
    bgemm(stream, hb, wT, bq + (size_t)l * D_, nullptr, qbuf, M_, D_, D_);
    tcast(stream, Wk + (size_t)l * D_ * KD_, wT, D_, KD_);
    bgemm(stream, hb, wT, bk + (size_t)l * KD_, nullptr, kbuf, M_, KD_, D_);
    tcast(stream, Wv + (size_t)l * D_ * KD_, wT, D_, KD_);
    bgemm(stream, hb, wT, bv + (size_t)l * KD_, nullptr, vbuf, M_, KD_, D_);
    {
      int npq = M_ * QH_ * 32;
      k_rope<<<dim3(npq / 256), dim3(256), 0, stream>>>(qbuf, QH_, npq);
      int npk = M_ * KVH_ * 32;
      k_rope<<<dim3(npk / 256), dim3(256), 0, stream>>>(kbuf, KVH_, npk);
    }
    k_attn2<<<dim3(B_ * QH_ * (S_ / 4)), dim3(256), 0, stream>>>(qbuf, kbuf, vbuf);
    cast_bf16(stream, qbuf, hb, (size_t)M_ * D_);
    tcast(stream, Wo + (size_t)l * D_ * D_, wT, D_, D_);
    bgemm(stream, hb, wT, bo + (size_t)l * D_, xbuf, xbuf, M_, D_, D_);

    // ---- MLP ----
    k_rms<<<dim3(M_), dim3(256), 0, stream>>>(xbuf, mlp_scale + (size_t)l * D_, hbuf);
    cast_bf16(stream, hbuf, hb, (size_t)M_ * D_);
    tcast(stream, W1 + (size_t)l * D_ * HID_, wT, D_, HID_);
    bgemm(stream, hb, wT, nullptr, nullptr, g1, M_, HID_, D_);
    gemm_nn(stream, hbuf, A1 + (size_t)l * D_ * R_, a1b + (size_t)l * R_, nullptr, ubuf, M_, R_, D_, 1.f, 0.f);
    gemm_nn(stream, ubuf, B1 + (size_t)l * R_ * HID_, b1b + (size_t)l * HID_, g1, g1, M_, HID_, R_, INV_ALPHA_, 1.f);
    tcast(stream, W2 + (size_t)l * D_ * HID_, wT, D_, HID_);
    bgemm(stream, hb, wT, nullptr, nullptr, g2, M_, HID_, D_);
    gemm_nn(stream, hbuf, A2 + (size_t)l * D_ * R_, a2b + (size_t)l * R_, nullptr, ubuf, M_, R_, D_, 1.f, 0.f);
    gemm_nn(stream, ubuf, B2 + (size_t)l * R_ * HID_, b2b + (size_t)l * HID_, g2, g2, M_, HID_, R_, INV_ALPHA_, 1.f);
    k_silumul<<<dim3(M_ * HID_ / 256), dim3(256), 0, stream>>>(g1, g2, M_ * HID_);
    cast_bf16(stream, g1, hb, (size_t)M_ * HID_);
    tcast(stream, W3 + (size_t)l * HID_ * D_, wT, HID_, D_);
    bgemm(stream, hb, wT, nullptr, xbuf, xbuf, M_, D_, HID_);
    gemm_nn(stream, g1, A3 + (size_t)l * HID_ * R_, a3b + (size_t)l * R_, nullptr, ubuf, M_, R_, HID_, 1.f, 0.f);
    gemm_nn(stream, ubuf, B3 + (size_t)l * R_ * D_, b3b + (size_t)l * D_, xbuf, xbuf, M_, D_, R_, INV_ALPHA_, 1.f);
  }

  // ---- final norm + vocab projection (emb is already [N=V][K=D]) ----
  k_rms<<<dim3(M_), dim3(256), 0, stream>>>(xbuf, final_scale, hbuf);
  cast_bf16(stream, hbuf, hb, (size_t)M_ * D_);
  cast_bf16(stream, emb, embT, (size_t)V_ * D_);
  bgemm(stream, hb, embT, nullptr, nullptr, out, M_, V_, D_);
}

// Round 3
// 2265.567 us; speedup vs baseline: 10.0363x; 3.0910x over previous
//
#include <hip/hip_runtime.h>
#include <hip/hip_bf16.h>
#include <math.h>

// ---- problem constants ----
constexpr int L_   = 2;
constexpr int D_   = 1024;
constexpr int HID_ = 4096;
constexpr int QH_  = 16;
constexpr int KVH_ = 4;
constexpr int V_   = 32000;
constexpr int B_   = 2;
constexpr int S_   = 2048;
constexpr int R_   = 20;
constexpr int HEAD_ = D_ / QH_;   // 64
constexpr int KD_   = KVH_ * HEAD_; // 256
constexpr int M_    = B_ * S_;    // 4096 tokens
constexpr float INV_ALPHA_ = 1.0f / 32.0f;
constexpr float LOG_STEP_ = 0.3381180865f;  // ln(50000)/32

typedef unsigned short ushort_t;
typedef __attribute__((ext_vector_type(8))) short bf16x8;
typedef __attribute__((ext_vector_type(4))) float f32x4;
typedef __attribute__((address_space(1))) const unsigned int gas_u32;
typedef __attribute__((address_space(3))) unsigned int las_u32;

__device__ __forceinline__ void gload16(const void* g, void* l) {
  __builtin_amdgcn_global_load_lds((gas_u32*)g, (las_u32*)l, 16, 0, 0);
}

__device__ __forceinline__ ushort_t f2bf(float f) {
  union { float f; unsigned int u; } c; c.f = f;
  unsigned int u = c.u + 0x7FFFu + ((c.u >> 16) & 1u);  // RNE
  return (ushort_t)(u >> 16);
}
__device__ __forceinline__ float bflo(unsigned int w) {
  union { unsigned int u; float f; } c; c.u = w << 16; return c.f;
}
__device__ __forceinline__ float bfhi(unsigned int w) {
  union { unsigned int u; float f; } c; c.u = w & 0xFFFF0000u; return c.f;
}

// ---------------- embedding gather ----------------
__global__ __launch_bounds__(256) void k_embed(const int* __restrict__ xs,
                                               const float* __restrict__ emb,
                                               float* __restrict__ x) {
  int i = blockIdx.x * blockDim.x + threadIdx.x;
  int total4 = M_ * D_ / 4;
  if (i >= total4) return;
  int row = i >> 8;
  int c4  = i & 255;
  const float4* src = reinterpret_cast<const float4*>(emb + (size_t)xs[row] * D_) + c4;
  reinterpret_cast<float4*>(x)[i] = *src;
}

// ---------------- RMSNorm ----------------
__global__ __launch_bounds__(256) void k_rms(const float* __restrict__ x,
                                             const float* __restrict__ scale,
                                             float* __restrict__ out) {
  int row = blockIdx.x;
  const float* xr = x + (size_t)row * D_;
  float ss = 0.f;
  for (int i = threadIdx.x; i < D_; i += 256) { float v = xr[i]; ss += v * v; }
  for (int off = 32; off > 0; off >>= 1) ss += __shfl_down(ss, off);
  __shared__ float red[5];
  if ((threadIdx.x & 63) == 0) red[threadIdx.x >> 6] = ss;
  __syncthreads();
  if (threadIdx.x == 0)
    red[4] = rsqrtf((red[0] + red[1] + red[2] + red[3]) * (1.0f / D_) + 1e-5f);
  __syncthreads();
  float inv = red[4];
  float* orow = out + (size_t)row * D_;
  for (int i = threadIdx.x; i < D_; i += 256) orow[i] = scale[i] * xr[i] * inv;
}

// ---------------- casts ----------------
__global__ __launch_bounds__(256) void k_cast(const float* __restrict__ in,
                                              ushort_t* __restrict__ out, int n8) {
  int i = blockIdx.x * blockDim.x + threadIdx.x;
  if (i >= n8) return;
  const float4* p = reinterpret_cast<const float4*>(in) + i * 2;
  float4 a = p[0], b = p[1];
  ushort_t r[8] = { f2bf(a.x), f2bf(a.y), f2bf(a.z), f2bf(a.w),
                    f2bf(b.x), f2bf(b.y), f2bf(b.z), f2bf(b.w) };
  reinterpret_cast<uint4*>(out)[i] = *reinterpret_cast<uint4*>(r);
}

// transpose+cast: in f32 [K][N] -> out bf16 [N][K]
__global__ __launch_bounds__(256) void k_tcast(const float* __restrict__ in,
                                               ushort_t* __restrict__ out,
                                               int K, int N) {
  __shared__ float t[32][33];
  int n0 = blockIdx.x * 32, k0 = blockIdx.y * 32;
  int c = threadIdx.x & 31, r0 = threadIdx.x >> 5;
#pragma unroll
  for (int rr = 0; rr < 4; ++rr) {
    int r = r0 + rr * 8;
    t[r][c] = in[(size_t)(k0 + r) * N + n0 + c];
  }
  __syncthreads();
#pragma unroll
  for (int rr = 0; rr < 4; ++rr) {
    int r = r0 + rr * 8;
    out[(size_t)(n0 + r) * K + k0 + c] = f2bf(t[c][r]);
  }
}

// ---------------- RoPE ----------------
__global__ __launch_bounds__(256) void k_rope(float* __restrict__ t, int heads, int npairs) {
  int i = blockIdx.x * blockDim.x + threadIdx.x;
  if (i >= npairs) return;
  int pi = i & 31;
  int h  = (i >> 5) % heads;
  int r  = i / (32 * heads);
  int s  = r & (S_ - 1);
  float freq = expf(-LOG_STEP_ * (float)pi);
  float ang = (float)s * freq;
  float sn, cs;
  sincosf(ang, &sn, &cs);
  size_t base = ((size_t)r * heads + h) * HEAD_ + 2 * pi;
  float t0 = t[base], t1 = t[base + 1];
  t[base]     = t0 * cs - t1 * sn;
  t[base + 1] = t0 * sn + t1 * cs;
}

// ---------------- K/V prep for MFMA attention ----------------
// Kb bf16 [b*KVH+kh][s][64] from kbuf f32 [token][256]
__global__ __launch_bounds__(256) void k_prep_k(const float* __restrict__ kf,
                                                ushort_t* __restrict__ Kb) {
  int idx = blockIdx.x * 256 + threadIdx.x;   // ushort8 chunk
  int o = idx * 8;
  int d0 = o & 63;
  int s = (o >> 6) & (S_ - 1);
  int bkh = o >> 17;
  const float* p = kf + (size_t)((bkh >> 2) * S_ + s) * KD_ + (bkh & 3) * 64 + d0;
  float4 f0 = *reinterpret_cast<const float4*>(p);
  float4 f1 = *reinterpret_cast<const float4*>(p + 4);
  ushort_t tq[8] = { f2bf(f0.x), f2bf(f0.y), f2bf(f0.z), f2bf(f0.w),
                     f2bf(f1.x), f2bf(f1.y), f2bf(f1.z), f2bf(f1.w) };
  reinterpret_cast<uint4*>(Kb)[idx] = *reinterpret_cast<uint4*>(tq);
}

// Vt bf16 [b*KVH+kh][d=64][s] (transposed) from vbuf f32 [token][256]
__global__ __launch_bounds__(256) void k_prep_v(const float* __restrict__ vf,
                                                ushort_t* __restrict__ Vt) {
  __shared__ float t[32][33];
  int s0 = blockIdx.x * 32, d0 = blockIdx.y * 32, bkh = blockIdx.z;
  int c = threadIdx.x & 31, r0 = threadIdx.x >> 5;
#pragma unroll
  for (int rr = 0; rr < 4; ++rr) {
    int r = r0 + rr * 8;
    t[r][c] = vf[(size_t)((bkh >> 2) * S_ + s0 + r) * KD_ + (bkh & 3) * 64 + d0 + c];
  }
  __syncthreads();
#pragma unroll
  for (int rr = 0; rr < 4; ++rr) {
    int r = r0 + rr * 8;
    Vt[(size_t)(bkh * 64 + d0 + r) * S_ + s0 + c] = f2bf(t[c][r]);
  }
}

// ---------------- MFMA flash attention ----------------
// Block: 4 waves, one (b,qh), 64 q rows (16/wave). KV tiles of 64.
// Q read from qbuf f32 (RoPE'd), output written as bf16 to obf [token][D].
__global__ __launch_bounds__(256) void k_attn3(const float* __restrict__ qbuf,
                                               const ushort_t* __restrict__ Kb,
                                               const ushort_t* __restrict__ Vt,
                                               ushort_t* __restrict__ obf) {
  __shared__ ushort_t Ks[64 * 64];   // [key][d-slot swizzled]
  __shared__ ushort_t Vs[64 * 64];   // [d][key-slot swizzled]
  __shared__ ushort_t Ps[4][16 * 64];

  int bid = blockIdx.x;
  int qt = 31 - (bid & 31);          // heavy blocks first
  int qh = (bid >> 5) & 15;
  int b  = bid >> 9;
  int kh = qh >> 2;
  int tid = threadIdx.x;
  int w = tid >> 6, lane = tid & 63;
  int q0 = qt * 64;

  const ushort_t* Kbh = Kb + (size_t)(b * KVH_ + kh) * S_ * 64;
  const ushort_t* Vth = Vt + (size_t)(b * KVH_ + kh) * 64 * S_;

  // Q A-frags (row = lane&15, k = kk*32 + (lane>>4)*8 .. +7), scaled by 1/8
  bf16x8 qa[2];
  {
    int tok = b * S_ + q0 + w * 16 + (lane & 15);
    const float* qp = qbuf + (size_t)tok * D_ + qh * 64 + (lane >> 4) * 8;
#pragma unroll
    for (int kk = 0; kk < 2; ++kk) {
      float4 f0 = *reinterpret_cast<const float4*>(qp + kk * 32);
      float4 f1 = *reinterpret_cast<const float4*>(qp + kk * 32 + 4);
      ushort_t tq[8] = { f2bf(f0.x * 0.125f), f2bf(f0.y * 0.125f),
                         f2bf(f0.z * 0.125f), f2bf(f0.w * 0.125f),
                         f2bf(f1.x * 0.125f), f2bf(f1.y * 0.125f),
                         f2bf(f1.z * 0.125f), f2bf(f1.w * 0.125f) };
      qa[kk] = *reinterpret_cast<const bf16x8*>(tq);
    }
  }

  f32x4 oacc[4];
#pragma unroll
  for (int j = 0; j < 4; ++j) oacc[j] = {0.f, 0.f, 0.f, 0.f};
  float m[4] = {-1e30f, -1e30f, -1e30f, -1e30f};
  float l[4] = {0.f, 0.f, 0.f, 0.f};

  // staging source swizzle: lds[row][slot] = glob[row][slot ^ (row&7)]
  const int srow = lane >> 3;                 // row within 8-row chunk
  const int soff = ((lane & 7) ^ srow) * 16;  // byte offset of 16B slot

  for (int t0 = 0; t0 <= q0; t0 += 64) {
#pragma unroll
    for (int r = 0; r < 2; ++r) {
      int c = w * 2 + r;
      const char* gk = (const char*)Kbh + (size_t)(t0 + c * 8 + srow) * 128 + soff;
      gload16(gk, (char*)Ks + c * 1024);
      const char* gv = (const char*)Vth + (size_t)(c * 8 + srow) * (S_ * 2) + (size_t)t0 * 2 + soff;
      gload16(gv, (char*)Vs + c * 1024);
    }
    __syncthreads();

    // ---- S = Q @ K^T ----
    f32x4 sacc[4];
#pragma unroll
    for (int j = 0; j < 4; ++j) sacc[j] = {0.f, 0.f, 0.f, 0.f};
#pragma unroll
    for (int kk = 0; kk < 2; ++kk) {
#pragma unroll
      for (int j = 0; j < 4; ++j) {
        int krow = j * 16 + (lane & 15);
        int chunk = kk * 4 + (lane >> 4);
        bf16x8 kf = *reinterpret_cast<const bf16x8*>(
            &Ks[krow * 64 + ((chunk ^ (krow & 7)) << 3)]);
        sacc[j] = __builtin_amdgcn_mfma_f32_16x16x32_bf16(qa[kk], kf, sacc[j], 0, 0, 0);
      }
    }
    if (t0 == q0) {  // causal mask (only final tile can be partial)
#pragma unroll
      for (int j = 0; j < 4; ++j)
#pragma unroll
        for (int e = 0; e < 4; ++e) {
          int keyr = j * 16 + (lane & 15);
          int qr = w * 16 + (lane >> 4) * 4 + e;
          if (keyr > qr) sacc[j][e] = -1e30f;
        }
    }

    // ---- online softmax (rows split over e; cols over j and 16-lane group) ----
    float corr[4];
#pragma unroll
    for (int e = 0; e < 4; ++e) {
      float mt = fmaxf(fmaxf(sacc[0][e], sacc[1][e]), fmaxf(sacc[2][e], sacc[3][e]));
#pragma unroll
      for (int off = 1; off < 16; off <<= 1) mt = fmaxf(mt, __shfl_xor(mt, off));
      float mn = fmaxf(m[e], mt);
      corr[e] = __expf(m[e] - mn);
      m[e] = mn;
    }
    float rs[4] = {0.f, 0.f, 0.f, 0.f};
#pragma unroll
    for (int j = 0; j < 4; ++j)
#pragma unroll
      for (int e = 0; e < 4; ++e) {
        float p = __expf(sacc[j][e] - m[e]);
        sacc[j][e] = p;
        rs[e] += p;
      }
#pragma unroll
    for (int e = 0; e < 4; ++e) {
#pragma unroll
      for (int off = 1; off < 16; off <<= 1) rs[e] += __shfl_xor(rs[e], off);
      l[e] = l[e] * corr[e] + rs[e];
    }
#pragma unroll
    for (int j = 0; j < 4; ++j)
#pragma unroll
      for (int e = 0; e < 4; ++e) oacc[j][e] *= corr[e];

    // ---- P -> LDS (bf16, swizzled) ----
#pragma unroll
    for (int j = 0; j < 4; ++j)
#pragma unroll
      for (int e = 0; e < 4; ++e) {
        int prow = (lane >> 4) * 4 + e;
        int pcol = j * 16 + (lane & 15);
        Ps[w][prow * 64 + (((pcol >> 3) ^ (prow & 7)) << 3) + (pcol & 7)] = f2bf(sacc[j][e]);
      }

    // ---- O += P @ V ----
    bf16x8 pa[2];
    int prow2 = lane & 15;
#pragma unroll
    for (int kk = 0; kk < 2; ++kk) {
      int chunk = kk * 4 + (lane >> 4);
      pa[kk] = *reinterpret_cast<const bf16x8*>(
          &Ps[w][prow2 * 64 + ((chunk ^ (prow2 & 7)) << 3)]);
    }
#pragma unroll
    for (int kk = 0; kk < 2; ++kk) {
#pragma unroll
      for (int jd = 0; jd < 4; ++jd) {
        int vrow = jd * 16 + (lane & 15);
        int chunk = kk * 4 + (lane >> 4);
        bf16x8 vf = *reinterpret_cast<const bf16x8*>(
            &Vs[vrow * 64 + ((chunk ^ (vrow & 7)) << 3)]);
        oacc[jd] = __builtin_amdgcn_mfma_f32_16x16x32_bf16(pa[kk], vf, oacc[jd], 0, 0, 0);
      }
    }
    __syncthreads();
  }

  // ---- write O as bf16 ----
#pragma unroll
  for (int e = 0; e < 4; ++e) {
    int tok = b * S_ + q0 + w * 16 + (lane >> 4) * 4 + e;
    float inv = 1.f / l[e];
#pragma unroll
    for (int jd = 0; jd < 4; ++jd) {
      int col = qh * 64 + jd * 16 + (lane & 15);
      obf[(size_t)tok * D_ + col] = f2bf(oacc[jd][e] * inv);
    }
  }
}

// ---------------- SiLU-mul ----------------
__global__ __launch_bounds__(256) void k_silumul(float* __restrict__ g1,
                                                 const float* __restrict__ g2, int n) {
  int i = blockIdx.x * blockDim.x + threadIdx.x;
  if (i >= n) return;
  float a = g1[i], b = g2[i];
  g1[i] = a * b / (1.f + __expf(-b));
}

// ---------------- LoRA-A helpers ----------------
// At bf16 [R][K] from A f32 [K][R]
__global__ __launch_bounds__(256) void k_trA(const float* __restrict__ A,
                                             ushort_t* __restrict__ At, int K) {
  int idx = blockIdx.x * 256 + threadIdx.x;
  if (idx >= K * R_) return;
  int k = idx / R_, r = idx - k * R_;
  At[(size_t)r * K + k] = f2bf(A[idx]);
}

// u[M][R] = hb[M][K] @ At[R][K]^T + ab ; one wave per row
template <int K>
__global__ __launch_bounds__(256) void k_loraA(const ushort_t* __restrict__ hbm,
                                               const ushort_t* __restrict__ At,
                                               const float* __restrict__ ab,
                                               float* __restrict__ u) {
  constexpr int E = K / 64;
  int row = blockIdx.x * 4 + (threadIdx.x >> 6);
  int lane = threadIdx.x & 63;
  float hf[E];
  {
    const uint4* hp = reinterpret_cast<const uint4*>(hbm + (size_t)row * K + lane * E);
#pragma unroll
    for (int i = 0; i < E / 8; ++i) {
      uint4 vv = hp[i];
      unsigned int wsv[4] = {vv.x, vv.y, vv.z, vv.w};
#pragma unroll
      for (int q = 0; q < 4; ++q) {
        hf[i * 8 + q * 2]     = bflo(wsv[q]);
        hf[i * 8 + q * 2 + 1] = bfhi(wsv[q]);
      }
    }
  }
  for (int r = 0; r < R_; ++r) {
    const uint4* ap = reinterpret_cast<const uint4*>(At + (size_t)r * K + lane * E);
    float acc = 0.f;
#pragma unroll
    for (int i = 0; i < E / 8; ++i) {
      uint4 av = ap[i];
      unsigned int wsv[4] = {av.x, av.y, av.z, av.w};
#pragma unroll
      for (int q = 0; q < 4; ++q) {
        acc = fmaf(hf[i * 8 + q * 2], bflo(wsv[q]), acc);
        acc = fmaf(hf[i * 8 + q * 2 + 1], bfhi(wsv[q]), acc);
      }
    }
#pragma unroll
    for (int off = 1; off < 64; off <<= 1) acc += __shfl_xor(acc, off);
    if (lane == 0) u[(size_t)row * R_ + r] = acc + ab[r];
  }
}

// ---------------- bf16 MFMA GEMM (m97 structure) ----------------
__global__ __launch_bounds__(256) void k_bgemm(const ushort_t* __restrict__ A,
                                               const ushort_t* __restrict__ Bt,
                                               const float* __restrict__ bias,
                                               const float* __restrict__ Cin,
                                               float* __restrict__ C,
                                               int M, int N, int K) {
  __shared__ ushort_t As[128 * 32];
  __shared__ ushort_t Bs[128 * 32];
  const int tid = threadIdx.x;
  const int lane = tid & 63;
  const int w = tid >> 6;
  const int wr = w >> 1, wc = w & 1;
  const int bm = blockIdx.y * 128, bn = blockIdx.x * 128;

  f32x4 acc[4][4];
#pragma unroll
  for (int i = 0; i < 4; ++i)
#pragma unroll
    for (int j = 0; j < 4; ++j) acc[i][j] = {0.f, 0.f, 0.f, 0.f};

  const int c0 = w * 2;
  const int srow = (lane >> 2);
  const int skcol = (lane & 3) * 8;

  for (int k0 = 0; k0 < K; k0 += 32) {
#pragma unroll
    for (int q = 0; q < 2; ++q) {
      int c = c0 + q;
      const ushort_t* ga = A + (size_t)(bm + c * 16 + srow) * K + k0 + skcol;
      gload16(ga, (char*)As + c * 1024);
      const ushort_t* gb = Bt + (size_t)(bn + c * 16 + srow) * K + k0 + skcol;
      gload16(gb, (char*)Bs + c * 1024);
    }
    __syncthreads();

    bf16x8 af[4], bf[4];
    const int koff = (lane >> 4) * 8;
    const int rsel = lane & 15;
#pragma unroll
    for (int i = 0; i < 4; ++i)
      af[i] = *reinterpret_cast<const bf16x8*>(&As[(wr * 64 + i * 16 + rsel) * 32 + koff]);
#pragma unroll
    for (int i = 0; i < 4; ++i)
      bf[i] = *reinterpret_cast<const bf16x8*>(&Bs[(wc * 64 + i * 16 + rsel) * 32 + koff]);
#pragma unroll
    for (int i = 0; i < 4; ++i)
#pragma unroll
      for (int j = 0; j < 4; ++j)
        acc[i][j] = __builtin_amdgcn_mfma_f32_16x16x32_bf16(af[i], bf[j], acc[i][j], 0, 0, 0);
    __syncthreads();
  }

#pragma unroll
  for (int i = 0; i < 4; ++i) {
    int row0 = bm + wr * 64 + i * 16 + (lane >> 4) * 4;
#pragma unroll
    for (int j = 0; j < 4; ++j) {
      int col = bn + wc * 64 + j * 16 + (lane & 15);
      float bv = bias ? bias[col] : 0.f;
#pragma unroll
      for (int e = 0; e < 4; ++e) {
        int row = row0 + e;
        float vv = acc[i][j][e] + bv;
        if (Cin) vv += Cin[(size_t)row * N + col];
        C[(size_t)row * N + col] = vv;
      }
    }
  }
}

// ---------------- guarded tiled f32 GEMM (LoRA-B only) ----------------
template <bool BT>
__global__ __launch_bounds__(256) void k_gemm(const float* __restrict__ A,
                                              const float* __restrict__ B,
                                              const float* __restrict__ bias,
                                              const float* __restrict__ Cin,
                                              float* __restrict__ C,
                                              int M, int N, int K,
                                              float alpha, float beta) {
  constexpr int BM = 128, BN = 128, BK = 8;
  __shared__ float As[BK][BM];
  __shared__ float Bs[BK][BN];
  const int tid = threadIdx.x;
  const int bm = blockIdx.y * BM;
  const int bn = blockIdx.x * BN;
  const int tx = tid & 15;
  const int ty = tid >> 4;
  float acc[8][8];
#pragma unroll
  for (int i = 0; i < 8; ++i)
#pragma unroll
    for (int j = 0; j < 8; ++j) acc[i][j] = 0.f;

  for (int k0 = 0; k0 < K; k0 += BK) {
    {
      const int r = tid >> 1;
      const int c = (tid & 1) * 4;
      float v0 = 0, v1 = 0, v2 = 0, v3 = 0;
      const int gr = bm + r;
      if (gr < M) {
        const float* p = A + (size_t)gr * K + k0 + c;
        if (k0 + c + 3 < K) {
          float4 t4 = *reinterpret_cast<const float4*>(p);
          v0 = t4.x; v1 = t4.y; v2 = t4.z; v3 = t4.w;
        } else {
          if (k0 + c + 0 < K) v0 = p[0];
          if (k0 + c + 1 < K) v1 = p[1];
          if (k0 + c + 2 < K) v2 = p[2];
          if (k0 + c + 3 < K) v3 = p[3];
        }
      }
      As[c + 0][r] = v0; As[c + 1][r] = v1; As[c + 2][r] = v2; As[c + 3][r] = v3;
    }
    {
      const int r = tid >> 5;
      const int c = (tid & 31) * 4;
      float v0 = 0, v1 = 0, v2 = 0, v3 = 0;
      const int gk = k0 + r;
      if (gk < K) {
        const float* p = B + (size_t)gk * N + bn + c;
        if (bn + c + 3 < N) {
          float4 t4 = *reinterpret_cast<const float4*>(p);
          v0 = t4.x; v1 = t4.y; v2 = t4.z; v3 = t4.w;
        } else {
          if (bn + c + 0 < N) v0 = p[0];
          if (bn + c + 1 < N) v1 = p[1];
          if (bn + c + 2 < N) v2 = p[2];
          if (bn + c + 3 < N) v3 = p[3];
        }
      }
      Bs[r][c + 0] = v0; Bs[r][c + 1] = v1; Bs[r][c + 2] = v2; Bs[r][c + 3] = v3;
    }
    __syncthreads();
#pragma unroll
    for (int kk = 0; kk < BK; ++kk) {
      float a[8], b[8];
      float4 a0 = *reinterpret_cast<const float4*>(&As[kk][ty * 8]);
      float4 a1 = *reinterpret_cast<const float4*>(&As[kk][ty * 8 + 4]);
      float4 b0 = *reinterpret_cast<const float4*>(&Bs[kk][tx * 8]);
      float4 b1 = *reinterpret_cast<const float4*>(&Bs[kk][tx * 8 + 4]);
      a[0] = a0.x; a[1] = a0.y; a[2] = a0.z; a[3] = a0.w;
      a[4] = a1.x; a[5] = a1.y; a[6] = a1.z; a[7] = a1.w;
      b[0] = b0.x; b[1] = b0.y; b[2] = b0.z; b[3] = b0.w;
      b[4] = b1.x; b[5] = b1.y; b[6] = b1.z; b[7] = b1.w;
#pragma unroll
      for (int i = 0; i < 8; ++i)
#pragma unroll
        for (int j = 0; j < 8; ++j) acc[i][j] = fmaf(a[i], b[j], acc[i][j]);
    }
    __syncthreads();
  }
#pragma unroll
  for (int i = 0; i < 8; ++i) {
    const int row = bm + ty * 8 + i;
    if (row >= M) continue;
#pragma unroll
    for (int j = 0; j < 8; ++j) {
      const int col = bn + tx * 8 + j;
      if (col >= N) continue;
      float vv = acc[i][j];
      if (bias) vv += bias[col];
      vv *= alpha;
      if (beta != 0.f) vv += beta * Cin[(size_t)row * N + col];
      C[(size_t)row * N + col] = vv;
    }
  }
}

static inline void gemm_nn(hipStream_t st, const float* A, const float* B,
                           const float* bias, const float* Cin, float* C,
                           int M, int N, int K, float alpha, float beta) {
  dim3 g((N + 127) / 128, (M + 127) / 128);
  k_gemm<false><<<g, 256, 0, st>>>(A, B, bias, Cin, C, M, N, K, alpha, beta);
}

static inline void bgemm(hipStream_t st, const ushort_t* A, const ushort_t* Bt,
                         const float* bias, const float* Cin, float* C,
                         int M, int N, int K) {
  dim3 g(N / 128, M / 128);
  k_bgemm<<<g, 256, 0, st>>>(A, Bt, bias, Cin, C, M, N, K);
}

static inline void tcast(hipStream_t st, const float* in, ushort_t* out, int K, int N) {
  dim3 g(N / 32, K / 32);
  k_tcast<<<g, 256, 0, st>>>(in, out, K, N);
}

static inline void cast_bf16(hipStream_t st, const float* in, ushort_t* out, size_t n) {
  int n8 = (int)(n / 8);
  k_cast<<<(n8 + 255) / 256, 256, 0, st>>>(in, out, n8);
}

extern "C" void kernel_launch(void* const* d_in, const int* in_sizes, int n_in,
                              void* d_out, int out_size, void* d_ws, size_t ws_size,
                              hipStream_t stream) {
  (void)in_sizes; (void)n_in; (void)out_size; (void)ws_size;
  const int*   xs  = (const int*)d_in[0];
  const float* emb = (const float*)d_in[1];
  const float* Wq  = (const float*)d_in[2];
  const float* bq  = (const float*)d_in[3];
  const float* Wk  = (const float*)d_in[4];
  const float* bk  = (const float*)d_in[5];
  const float* Wv  = (const float*)d_in[6];
  const float* bv  = (const float*)d_in[7];
  const float* Wo  = (const float*)d_in[8];
  const float* bo  = (const float*)d_in[9];
  const float* att_scale   = (const float*)d_in[10];
  const float* mlp_scale   = (const float*)d_in[11];
  const float* final_scale = (const float*)d_in[12];
  const float* W1  = (const float*)d_in[13];
  const float* A1  = (const float*)d_in[14];
  const float* a1b = (const float*)d_in[15];
  const float* B1  = (const float*)d_in[16];
  const float* b1b = (const float*)d_in[17];
  const float* W2  = (const float*)d_in[18];
  const float* A2  = (const float*)d_in[19];
  const float* a2b = (const float*)d_in[20];
  const float* B2  = (const float*)d_in[21];
  const float* b2b = (const float*)d_in[22];
  const float* W3  = (const float*)d_in[23];
  const float* A3  = (const float*)d_in[24];
  const float* a3b = (const float*)d_in[25];
  const float* B3  = (const float*)d_in[26];
  const float* b3b = (const float*)d_in[27];
  float* out = (float*)d_out;

  // f32 workspace
  float* ws   = (float*)d_ws;
  float* xbuf = ws;
  float* hbuf = xbuf + (size_t)M_ * D_;
  float* qbuf = hbuf + (size_t)M_ * D_;
  float* kbuf = qbuf + (size_t)M_ * D_;
  float* vbuf = kbuf + (size_t)M_ * KD_;
  float* g1   = vbuf + (size_t)M_ * KD_;
  float* g2   = g1 + (size_t)M_ * HID_;
  float* ubuf = g2 + (size_t)M_ * HID_;
  // bf16 scratch
  ushort_t* hb   = (ushort_t*)(ubuf + (size_t)M_ * R_);   // M*HID ushorts
  ushort_t* wT   = hb + (size_t)M_ * HID_;                // HID*D ushorts
  ushort_t* At   = wT + (size_t)HID_ * D_;                // R*HID ushorts
  ushort_t* embT = (ushort_t*)g2;                         // alias (final only)
  // K/V bf16 alias into g1 (dead during attention phase)
  ushort_t* Kb = (ushort_t*)g1;                           // B*KVH*S*64
  ushort_t* Vt = Kb + (size_t)B_ * KVH_ * S_ * 64;        // B*KVH*64*S

  k_embed<<<dim3(M_ * D_ / 4 / 256), dim3(256), 0, stream>>>(xs, emb, xbuf);

  for (int l = 0; l < L_; ++l) {
    // ---- attention ----
    k_rms<<<dim3(M_), dim3(256), 0, stream>>>(xbuf, att_scale + (size_t)l * D_, hbuf);
    cast_bf16(stream, hbuf, hb, (size_t)M_ * D_);
    tcast(stream, Wq + (size_t)l * D_ * D_, wT, D_, D_);
    bgemm(stream, hb, wT, bq + (size_t)l * D_, nullptr, qbuf, M_, D_, D_);
    tcast(stream, Wk + (size_t)l * D_ * KD_, wT, D_, KD_);
    bgemm(stream, hb, wT, bk + (size_t)l * KD_, nullptr, kbuf, M_, KD_, D_);
    tcast(stream, Wv + (size_t)l * D_ * KD_, wT, D_, KD_);
    bgemm(stream, hb, wT, bv + (size_t)l * KD_, nullptr, vbuf, M_, KD_, D_);
    {
      int npq = M_ * QH_ * 32;
      k_rope<<<dim3(npq / 256), dim3(256), 0, stream>>>(qbuf, QH_, npq);
      int npk = M_ * KVH_ * 32;
      k_rope<<<dim3(npk / 256), dim3(256), 0, stream>>>(kbuf, KVH_, npk);
    }
    k_prep_k<<<dim3(B_ * KVH_ * S_ * 64 / 8 / 256), dim3(256), 0, stream>>>(kbuf, Kb);
    k_prep_v<<<dim3(S_ / 32, 2, B_ * KVH_), dim3(256), 0, stream>>>(vbuf, Vt);
    k_attn3<<<dim3(B_ * QH_ * (S_ / 64)), dim3(256), 0, stream>>>(qbuf, Kb, Vt, hb);
    tcast(stream, Wo + (size_t)l * D_ * D_, wT, D_, D_);
    bgemm(stream, hb, wT, bo + (size_t)l * D_, xbuf, xbuf, M_, D_, D_);

    // ---- MLP ----
    k_rms<<<dim3(M_), dim3(256), 0, stream>>>(xbuf, mlp_scale + (size_t)l * D_, hbuf);
    cast_bf16(stream, hbuf, hb, (size_t)M_ * D_);
    tcast(stream, W1 + (size_t)l * D_ * HID_, wT, D_, HID_);
    bgemm(stream, hb, wT, nullptr, nullptr, g1, M_, HID_, D_);
    k_trA<<<dim3((D_ * R_ + 255) / 256), dim3(256), 0, stream>>>(A1 + (size_t)l * D_ * R_, At, D_);
    k_loraA<D_><<<dim3(M_ / 4), dim3(256), 0, stream>>>(hb, At, a1b + (size_t)l * R_, ubuf);
    gemm_nn(stream, ubuf, B1 + (size_t)l * R_ * HID_, b1b + (size_t)l * HID_, g1, g1, M_, HID_, R_, INV_ALPHA_, 1.f);
    tcast(stream, W2 + (size_t)l * D_ * HID_, wT, D_, HID_);
    bgemm(stream, hb, wT, nullptr, nullptr, g2, M_, HID_, D_);
    k_trA<<<dim3((D_ * R_ + 255) / 256), dim3(256), 0, stream>>>(A2 + (size_t)l * D_ * R_, At, D_);
    k_loraA<D_><<<dim3(M_ / 4), dim3(256), 0, stream>>>(hb, At, a2b + (size_t)l * R_, ubuf);
    gemm_nn(stream, ubuf, B2 + (size_t)l * R_ * HID_, b2b + (size_t)l * HID_, g2, g2, M_, HID_, R_, INV_ALPHA_, 1.f);
    k_silumul<<<dim3(M_ * HID_ / 256), dim3(256), 0, stream>>>(g1, g2, M_ * HID_);
    cast_bf16(stream, g1, hb, (size_t)M_ * HID_);
    tcast(stream, W3 + (size_t)l * HID_ * D_, wT, HID_, D_);
    bgemm(stream, hb, wT, nullptr, xbuf, xbuf, M_, D_, HID_);
    k_trA<<<dim3((HID_ * R_ + 255) / 256), dim3(256), 0, stream>>>(A3 + (size_t)l * HID_ * R_, At, HID_);
    k_loraA<HID_><<<dim3(M_ / 4), dim3(256), 0, stream>>>(hb, At, a3b + (size_t)l * R_, ubuf);
    gemm_nn(stream, ubuf, B3 + (size_t)l * R_ * D_, b3b + (size_t)l * D_, xbuf, xbuf, M_, D_, R_, INV_ALPHA_, 1.f);
  }

  // ---- final norm + vocab projection ----
  k_rms<<<dim3(M_), dim3(256), 0, stream>>>(xbuf, final_scale, hbuf);
  cast_bf16(stream, hbuf, hb, (size_t)M_ * D_);
  cast_bf16(stream, emb, embT, (size_t)V_ * D_);
  bgemm(stream, hb, embT, nullptr, nullptr, out, M_, V_, D_);
}

// Round 4
// 1842.336 us; speedup vs baseline: 12.3419x; 1.2297x over previous
//
#include <hip/hip_runtime.h>
#include <hip/hip_bf16.h>
#include <math.h>

// ---- problem constants ----
constexpr int L_   = 2;
constexpr int D_   = 1024;
constexpr int HID_ = 4096;
constexpr int QH_  = 16;
constexpr int KVH_ = 4;
constexpr int V_   = 32000;
constexpr int B_   = 2;
constexpr int S_   = 2048;
constexpr int R_   = 20;
constexpr int HEAD_ = D_ / QH_;   // 64
constexpr int KD_   = KVH_ * HEAD_; // 256
constexpr int M_    = B_ * S_;    // 4096 tokens
constexpr float INV_ALPHA_ = 1.0f / 32.0f;
constexpr float LOG_STEP_ = 0.3381180865f;  // ln(50000)/32

typedef unsigned short ushort_t;
typedef __attribute__((ext_vector_type(8))) short bf16x8;
typedef __attribute__((ext_vector_type(4))) float f32x4;
typedef __attribute__((address_space(1))) const unsigned int gas_u32;
typedef __attribute__((address_space(3))) unsigned int las_u32;

__device__ __forceinline__ void gload16(const void* g, void* l) {
  __builtin_amdgcn_global_load_lds((gas_u32*)g, (las_u32*)l, 16, 0, 0);
}

__device__ __forceinline__ ushort_t f2bf(float f) {
  union { float f; unsigned int u; } c; c.f = f;
  unsigned int u = c.u + 0x7FFFu + ((c.u >> 16) & 1u);  // RNE
  return (ushort_t)(u >> 16);
}
__device__ __forceinline__ float bflo(unsigned int w) {
  union { unsigned int u; float f; } c; c.u = w << 16; return c.f;
}
__device__ __forceinline__ float bfhi(unsigned int w) {
  union { unsigned int u; float f; } c; c.u = w & 0xFFFF0000u; return c.f;
}

// ---------------- embedding gather ----------------
__global__ __launch_bounds__(256) void k_embed(const int* __restrict__ xs,
                                               const float* __restrict__ emb,
                                               float* __restrict__ x) {
  int i = blockIdx.x * blockDim.x + threadIdx.x;
  int total4 = M_ * D_ / 4;
  if (i >= total4) return;
  int row = i >> 8;
  int c4  = i & 255;
  const float4* src = reinterpret_cast<const float4*>(emb + (size_t)xs[row] * D_) + c4;
  reinterpret_cast<float4*>(x)[i] = *src;
}

// ---------------- RMSNorm (writes bf16 directly) ----------------
__global__ __launch_bounds__(256) void k_rms(const float* __restrict__ x,
                                             const float* __restrict__ scale,
                                             ushort_t* __restrict__ out) {
  int row = blockIdx.x;
  const float* xr = x + (size_t)row * D_;
  float ss = 0.f;
  for (int i = threadIdx.x; i < D_; i += 256) { float v = xr[i]; ss += v * v; }
  for (int off = 32; off > 0; off >>= 1) ss += __shfl_down(ss, off);
  __shared__ float red[5];
  if ((threadIdx.x & 63) == 0) red[threadIdx.x >> 6] = ss;
  __syncthreads();
  if (threadIdx.x == 0)
    red[4] = rsqrtf((red[0] + red[1] + red[2] + red[3]) * (1.0f / D_) + 1e-5f);
  __syncthreads();
  float inv = red[4];
  ushort_t* orow = out + (size_t)row * D_;
  for (int i = threadIdx.x; i < D_; i += 256) orow[i] = f2bf(scale[i] * xr[i] * inv);
}

// ---------------- cast (emb only) ----------------
__global__ __launch_bounds__(256) void k_cast(const float* __restrict__ in,
                                              ushort_t* __restrict__ out, int n8) {
  int i = blockIdx.x * blockDim.x + threadIdx.x;
  if (i >= n8) return;
  const float4* p = reinterpret_cast<const float4*>(in) + i * 2;
  float4 a = p[0], b = p[1];
  ushort_t r[8] = { f2bf(a.x), f2bf(a.y), f2bf(a.z), f2bf(a.w),
                    f2bf(b.x), f2bf(b.y), f2bf(b.z), f2bf(b.w) };
  reinterpret_cast<uint4*>(out)[i] = *reinterpret_cast<uint4*>(r);
}

// transpose+cast: in f32 [K][N] -> out bf16 [N][K]
__global__ __launch_bounds__(256) void k_tcast(const float* __restrict__ in,
                                               ushort_t* __restrict__ out,
                                               int K, int N) {
  __shared__ float t[32][33];
  int n0 = blockIdx.x * 32, k0 = blockIdx.y * 32;
  int c = threadIdx.x & 31, r0 = threadIdx.x >> 5;
#pragma unroll
  for (int rr = 0; rr < 4; ++rr) {
    int r = r0 + rr * 8;
    t[r][c] = in[(size_t)(k0 + r) * N + n0 + c];
  }
  __syncthreads();
#pragma unroll
  for (int rr = 0; rr < 4; ++rr) {
    int r = r0 + rr * 8;
    out[(size_t)(n0 + r) * K + k0 + c] = f2bf(t[c][r]);
  }
}

// ---------------- RoPE (Q only, in-place f32) ----------------
__global__ __launch_bounds__(256) void k_rope(float* __restrict__ t, int heads, int npairs) {
  int i = blockIdx.x * blockDim.x + threadIdx.x;
  if (i >= npairs) return;
  int pi = i & 31;
  int h  = (i >> 5) % heads;
  int r  = i / (32 * heads);
  int s  = r & (S_ - 1);
  float freq = expf(-LOG_STEP_ * (float)pi);
  float ang = (float)s * freq;
  float sn, cs;
  sincosf(ang, &sn, &cs);
  size_t base = ((size_t)r * heads + h) * HEAD_ + 2 * pi;
  float t0 = t[base], t1 = t[base + 1];
  t[base]     = t0 * cs - t1 * sn;
  t[base + 1] = t0 * sn + t1 * cs;
}

// ---------------- fused RoPE + K prep: kbuf f32 -> Kb bf16 [bkh][s][64] ----------------
__global__ __launch_bounds__(256) void k_ropeprep_k(const float* __restrict__ kf,
                                                    ushort_t* __restrict__ Kb) {
  int i = blockIdx.x * 256 + threadIdx.x;   // pair index
  int pi = i & 31;
  int kh = (i >> 5) & 3;
  int s  = (i >> 7) & (S_ - 1);
  int b  = i >> 18;
  float freq = expf(-LOG_STEP_ * (float)pi);
  float ang = (float)s * freq;
  float sn, cs;
  sincosf(ang, &sn, &cs);
  const float* p = kf + (size_t)(b * S_ + s) * KD_ + kh * 64 + 2 * pi;
  float t0 = p[0], t1 = p[1];
  float r0 = t0 * cs - t1 * sn;
  float r1 = t0 * sn + t1 * cs;
  ushort_t* q = Kb + (size_t)((b * KVH_ + kh) * S_ + s) * 64 + 2 * pi;
  q[0] = f2bf(r0);
  q[1] = f2bf(r1);
}

// Vt bf16 [bkh][d=64][s] (transposed) from vbuf f32 [token][256]
__global__ __launch_bounds__(256) void k_prep_v(const float* __restrict__ vf,
                                                ushort_t* __restrict__ Vt) {
  __shared__ float t[32][33];
  int s0 = blockIdx.x * 32, d0 = blockIdx.y * 32, bkh = blockIdx.z;
  int c = threadIdx.x & 31, r0 = threadIdx.x >> 5;
#pragma unroll
  for (int rr = 0; rr < 4; ++rr) {
    int r = r0 + rr * 8;
    t[r][c] = vf[(size_t)((bkh >> 2) * S_ + s0 + r) * KD_ + (bkh & 3) * 64 + d0 + c];
  }
  __syncthreads();
#pragma unroll
  for (int rr = 0; rr < 4; ++rr) {
    int r = r0 + rr * 8;
    Vt[(size_t)(bkh * 64 + d0 + r) * S_ + s0 + c] = f2bf(t[c][r]);
  }
}

// ---------------- MFMA flash attention ----------------
__global__ __launch_bounds__(256) void k_attn3(const float* __restrict__ qbuf,
                                               const ushort_t* __restrict__ Kb,
                                               const ushort_t* __restrict__ Vt,
                                               ushort_t* __restrict__ obf) {
  __shared__ ushort_t Ks[64 * 64];
  __shared__ ushort_t Vs[64 * 64];
  __shared__ ushort_t Ps[4][16 * 64];

  int bid = blockIdx.x;
  int qt = 31 - (bid & 31);          // heavy blocks first
  int qh = (bid >> 5) & 15;
  int b  = bid >> 9;
  int kh = qh >> 2;
  int tid = threadIdx.x;
  int w = tid >> 6, lane = tid & 63;
  int q0 = qt * 64;

  const ushort_t* Kbh = Kb + (size_t)(b * KVH_ + kh) * S_ * 64;
  const ushort_t* Vth = Vt + (size_t)(b * KVH_ + kh) * 64 * S_;

  bf16x8 qa[2];
  {
    int tok = b * S_ + q0 + w * 16 + (lane & 15);
    const float* qp = qbuf + (size_t)tok * D_ + qh * 64 + (lane >> 4) * 8;
#pragma unroll
    for (int kk = 0; kk < 2; ++kk) {
      float4 f0 = *reinterpret_cast<const float4*>(qp + kk * 32);
      float4 f1 = *reinterpret_cast<const float4*>(qp + kk * 32 + 4);
      ushort_t tq[8] = { f2bf(f0.x * 0.125f), f2bf(f0.y * 0.125f),
                         f2bf(f0.z * 0.125f), f2bf(f0.w * 0.125f),
                         f2bf(f1.x * 0.125f), f2bf(f1.y * 0.125f),
                         f2bf(f1.z * 0.125f), f2bf(f1.w * 0.125f) };
      qa[kk] = *reinterpret_cast<const bf16x8*>(tq);
    }
  }

  f32x4 oacc[4];
#pragma unroll
  for (int j = 0; j < 4; ++j) oacc[j] = {0.f, 0.f, 0.f, 0.f};
  float m[4] = {-1e30f, -1e30f, -1e30f, -1e30f};
  float l[4] = {0.f, 0.f, 0.f, 0.f};

  const int srow = lane >> 3;
  const int soff = ((lane & 7) ^ srow) * 16;

  for (int t0 = 0; t0 <= q0; t0 += 64) {
#pragma unroll
    for (int r = 0; r < 2; ++r) {
      int c = w * 2 + r;
      const char* gk = (const char*)Kbh + (size_t)(t0 + c * 8 + srow) * 128 + soff;
      gload16(gk, (char*)Ks + c * 1024);
      const char* gv = (const char*)Vth + (size_t)(c * 8 + srow) * (S_ * 2) + (size_t)t0 * 2 + soff;
      gload16(gv, (char*)Vs + c * 1024);
    }
    __syncthreads();

    f32x4 sacc[4];
#pragma unroll
    for (int j = 0; j < 4; ++j) sacc[j] = {0.f, 0.f, 0.f, 0.f};
#pragma unroll
    for (int kk = 0; kk < 2; ++kk) {
#pragma unroll
      for (int j = 0; j < 4; ++j) {
        int krow = j * 16 + (lane & 15);
        int chunk = kk * 4 + (lane >> 4);
        bf16x8 kf = *reinterpret_cast<const bf16x8*>(
            &Ks[krow * 64 + ((chunk ^ (krow & 7)) << 3)]);
        sacc[j] = __builtin_amdgcn_mfma_f32_16x16x32_bf16(qa[kk], kf, sacc[j], 0, 0, 0);
      }
    }
    if (t0 == q0) {
#pragma unroll
      for (int j = 0; j < 4; ++j)
#pragma unroll
        for (int e = 0; e < 4; ++e) {
          int keyr = j * 16 + (lane & 15);
          int qr = w * 16 + (lane >> 4) * 4 + e;
          if (keyr > qr) sacc[j][e] = -1e30f;
        }
    }

    float corr[4];
#pragma unroll
    for (int e = 0; e < 4; ++e) {
      float mt = fmaxf(fmaxf(sacc[0][e], sacc[1][e]), fmaxf(sacc[2][e], sacc[3][e]));
#pragma unroll
      for (int off = 1; off < 16; off <<= 1) mt = fmaxf(mt, __shfl_xor(mt, off));
      float mn = fmaxf(m[e], mt);
      corr[e] = __expf(m[e] - mn);
      m[e] = mn;
    }
    float rs[4] = {0.f, 0.f, 0.f, 0.f};
#pragma unroll
    for (int j = 0; j < 4; ++j)
#pragma unroll
      for (int e = 0; e < 4; ++e) {
        float p = __expf(sacc[j][e] - m[e]);
        sacc[j][e] = p;
        rs[e] += p;
      }
#pragma unroll
    for (int e = 0; e < 4; ++e) {
#pragma unroll
      for (int off = 1; off < 16; off <<= 1) rs[e] += __shfl_xor(rs[e], off);
      l[e] = l[e] * corr[e] + rs[e];
    }
#pragma unroll
    for (int j = 0; j < 4; ++j)
#pragma unroll
      for (int e = 0; e < 4; ++e) oacc[j][e] *= corr[e];

#pragma unroll
    for (int j = 0; j < 4; ++j)
#pragma unroll
      for (int e = 0; e < 4; ++e) {
        int prow = (lane >> 4) * 4 + e;
        int pcol = j * 16 + (lane & 15);
        Ps[w][prow * 64 + (((pcol >> 3) ^ (prow & 7)) << 3) + (pcol & 7)] = f2bf(sacc[j][e]);
      }

    bf16x8 pa[2];
    int prow2 = lane & 15;
#pragma unroll
    for (int kk = 0; kk < 2; ++kk) {
      int chunk = kk * 4 + (lane >> 4);
      pa[kk] = *reinterpret_cast<const bf16x8*>(
          &Ps[w][prow2 * 64 + ((chunk ^ (prow2 & 7)) << 3)]);
    }
#pragma unroll
    for (int kk = 0; kk < 2; ++kk) {
#pragma unroll
      for (int jd = 0; jd < 4; ++jd) {
        int vrow = jd * 16 + (lane & 15);
        int chunk = kk * 4 + (lane >> 4);
        bf16x8 vf = *reinterpret_cast<const bf16x8*>(
            &Vs[vrow * 64 + ((chunk ^ (vrow & 7)) << 3)]);
        oacc[jd] = __builtin_amdgcn_mfma_f32_16x16x32_bf16(pa[kk], vf, oacc[jd], 0, 0, 0);
      }
    }
    __syncthreads();
  }

#pragma unroll
  for (int e = 0; e < 4; ++e) {
    int tok = b * S_ + q0 + w * 16 + (lane >> 4) * 4 + e;
    float inv = 1.f / l[e];
#pragma unroll
    for (int jd = 0; jd < 4; ++jd) {
      int col = qh * 64 + jd * 16 + (lane & 15);
      obf[(size_t)tok * D_ + col] = f2bf(oacc[jd][e] * inv);
    }
  }
}

// ---------------- SiLU-mul -> bf16 ----------------
__global__ __launch_bounds__(256) void k_silumul(const float* __restrict__ g1,
                                                 const float* __restrict__ g2,
                                                 ushort_t* __restrict__ out) {
  int i = blockIdx.x * 256 + threadIdx.x;   // float4 chunk
  float4 a = reinterpret_cast<const float4*>(g1)[i];
  float4 b = reinterpret_cast<const float4*>(g2)[i];
  ushort_t r[4] = {
    f2bf(a.x * b.x / (1.f + __expf(-b.x))),
    f2bf(a.y * b.y / (1.f + __expf(-b.y))),
    f2bf(a.z * b.z / (1.f + __expf(-b.z))),
    f2bf(a.w * b.w / (1.f + __expf(-b.w))) };
  reinterpret_cast<uint2*>(out)[i] = *reinterpret_cast<uint2*>(r);
}

// ---------------- LoRA-A helpers ----------------
__global__ __launch_bounds__(256) void k_trA(const float* __restrict__ A,
                                             ushort_t* __restrict__ At, int K) {
  int idx = blockIdx.x * 256 + threadIdx.x;
  if (idx >= K * R_) return;
  int k = idx / R_, r = idx - k * R_;
  At[(size_t)r * K + k] = f2bf(A[idx]);
}

// u[M][R] = hb[M][K] @ At[R][K]^T + ab ; one wave per row
template <int K>
__global__ __launch_bounds__(256) void k_loraA(const ushort_t* __restrict__ hbm,
                                               const ushort_t* __restrict__ At,
                                               const float* __restrict__ ab,
                                               float* __restrict__ u) {
  constexpr int E = K / 64;
  int row = blockIdx.x * 4 + (threadIdx.x >> 6);
  int lane = threadIdx.x & 63;
  float hf[E];
  {
    const uint4* hp = reinterpret_cast<const uint4*>(hbm + (size_t)row * K + lane * E);
#pragma unroll
    for (int i = 0; i < E / 8; ++i) {
      uint4 vv = hp[i];
      unsigned int wsv[4] = {vv.x, vv.y, vv.z, vv.w};
#pragma unroll
      for (int q = 0; q < 4; ++q) {
        hf[i * 8 + q * 2]     = bflo(wsv[q]);
        hf[i * 8 + q * 2 + 1] = bfhi(wsv[q]);
      }
    }
  }
  for (int r = 0; r < R_; ++r) {
    const uint4* ap = reinterpret_cast<const uint4*>(At + (size_t)r * K + lane * E);
    float acc = 0.f;
#pragma unroll
    for (int i = 0; i < E / 8; ++i) {
      uint4 av = ap[i];
      unsigned int wsv[4] = {av.x, av.y, av.z, av.w};
#pragma unroll
      for (int q = 0; q < 4; ++q) {
        acc = fmaf(hf[i * 8 + q * 2], bflo(wsv[q]), acc);
        acc = fmaf(hf[i * 8 + q * 2 + 1], bfhi(wsv[q]), acc);
      }
    }
#pragma unroll
    for (int off = 1; off < 64; off <<= 1) acc += __shfl_xor(acc, off);
    if (lane == 0) u[(size_t)row * R_ + r] = acc + ab[r];
  }
}

// ---------------- bf16 MFMA GEMM (m97 structure + XCD swizzle + LoRA fusion) ----------------
// C = A @ Bt^T (+bias) (+ (u@Bl + lb)/ALPHA if LORA) (+Cin)
template <bool LORA>
__global__ __launch_bounds__(256) void k_bgemm(const ushort_t* __restrict__ A,
                                               const ushort_t* __restrict__ Bt,
                                               const float* __restrict__ bias,
                                               const float* __restrict__ u,
                                               const float* __restrict__ Bl,
                                               const float* __restrict__ lb,
                                               const float* __restrict__ Cin,
                                               float* __restrict__ C,
                                               int M, int N, int K) {
  __shared__ ushort_t As[128 * 32];
  __shared__ ushort_t Bs[128 * 32];
  const int tid = threadIdx.x;
  const int lane = tid & 63;
  const int w = tid >> 6;
  const int wr = w >> 1, wc = w & 1;

  // bijective XCD-aware swizzle (m204)
  unsigned nwg = gridDim.x * gridDim.y;
  unsigned orig = blockIdx.y * gridDim.x + blockIdx.x;
  unsigned qq = nwg >> 3, r8 = nwg & 7;
  unsigned xcd = orig & 7, loc = orig >> 3;
  unsigned swz = (xcd < r8 ? xcd * (qq + 1) : r8 * (qq + 1) + (xcd - r8) * qq) + loc;
  const int bm = (int)(swz / gridDim.x) * 128;
  const int bn = (int)(swz % gridDim.x) * 128;

  f32x4 acc[4][4];
#pragma unroll
  for (int i = 0; i < 4; ++i)
#pragma unroll
    for (int j = 0; j < 4; ++j) acc[i][j] = {0.f, 0.f, 0.f, 0.f};

  const int c0 = w * 2;
  const int srow = (lane >> 2);
  const int skcol = (lane & 3) * 8;

  for (int k0 = 0; k0 < K; k0 += 32) {
#pragma unroll
    for (int q = 0; q < 2; ++q) {
      int c = c0 + q;
      const ushort_t* ga = A + (size_t)(bm + c * 16 + srow) * K + k0 + skcol;
      gload16(ga, (char*)As + c * 1024);
      const ushort_t* gb = Bt + (size_t)(bn + c * 16 + srow) * K + k0 + skcol;
      gload16(gb, (char*)Bs + c * 1024);
    }
    __syncthreads();

    bf16x8 af[4], bf[4];
    const int koff = (lane >> 4) * 8;
    const int rsel = lane & 15;
#pragma unroll
    for (int i = 0; i < 4; ++i)
      af[i] = *reinterpret_cast<const bf16x8*>(&As[(wr * 64 + i * 16 + rsel) * 32 + koff]);
#pragma unroll
    for (int i = 0; i < 4; ++i)
      bf[i] = *reinterpret_cast<const bf16x8*>(&Bs[(wc * 64 + i * 16 + rsel) * 32 + koff]);
#pragma unroll
    for (int i = 0; i < 4; ++i)
#pragma unroll
      for (int j = 0; j < 4; ++j)
        acc[i][j] = __builtin_amdgcn_mfma_f32_16x16x32_bf16(af[i], bf[j], acc[i][j], 0, 0, 0);
    __syncthreads();
  }

  if constexpr (LORA) {
    __shared__ float Us[128 * R_];    // [m][r]
    __shared__ float Bls[R_ * 128];   // [r][n]
    for (int t = tid; t < 128 * R_; t += 256) {
      Us[t] = u[(size_t)bm * R_ + t];
      int rr = t >> 7, nn = t & 127;
      Bls[t] = Bl[(size_t)rr * N + bn + nn];
    }
    __syncthreads();
#pragma unroll
    for (int i = 0; i < 4; ++i) {
      int rl0 = wr * 64 + i * 16 + (lane >> 4) * 4;
#pragma unroll
      for (int e = 0; e < 4; ++e) {
        int rl = rl0 + e;
        float u20[R_];
#pragma unroll
        for (int r = 0; r < R_; ++r) u20[r] = Us[rl * R_ + r];
#pragma unroll
        for (int j = 0; j < 4; ++j) {
          int cl = wc * 64 + j * 16 + (lane & 15);
          float ud = lb[bn + cl];
#pragma unroll
          for (int r = 0; r < R_; ++r) ud = fmaf(u20[r], Bls[r * 128 + cl], ud);
          int row = bm + rl, col = bn + cl;
          float vv = acc[i][j][e] + ud * INV_ALPHA_;
          if (Cin) vv += Cin[(size_t)row * N + col];
          C[(size_t)row * N + col] = vv;
        }
      }
    }
  } else {
#pragma unroll
    for (int i = 0; i < 4; ++i) {
      int row0 = bm + wr * 64 + i * 16 + (lane >> 4) * 4;
#pragma unroll
      for (int j = 0; j < 4; ++j) {
        int col = bn + wc * 64 + j * 16 + (lane & 15);
        float bv = bias ? bias[col] : 0.f;
#pragma unroll
        for (int e = 0; e < 4; ++e) {
          int row = row0 + e;
          float vv = acc[i][j][e] + bv;
          if (Cin) vv += Cin[(size_t)row * N + col];
          C[(size_t)row * N + col] = vv;
        }
      }
    }
  }
}

static inline void bgemm(hipStream_t st, const ushort_t* A, const ushort_t* Bt,
                         const float* bias, const float* Cin, float* C,
                         int M, int N, int K) {
  dim3 g(N / 128, M / 128);
  k_bgemm<false><<<g, 256, 0, st>>>(A, Bt, bias, nullptr, nullptr, nullptr, Cin, C, M, N, K);
}
static inline void bgemm_lora(hipStream_t st, const ushort_t* A, const ushort_t* Bt,
                              const float* u, const float* Bl, const float* lb,
                              const float* Cin, float* C, int M, int N, int K) {
  dim3 g(N / 128, M / 128);
  k_bgemm<true><<<g, 256, 0, st>>>(A, Bt, nullptr, u, Bl, lb, Cin, C, M, N, K);
}
static inline void tcast(hipStream_t st, const float* in, ushort_t* out, int K, int N) {
  dim3 g(N / 32, K / 32);
  k_tcast<<<g, 256, 0, st>>>(in, out, K, N);
}

extern "C" void kernel_launch(void* const* d_in, const int* in_sizes, int n_in,
                              void* d_out, int out_size, void* d_ws, size_t ws_size,
                              hipStream_t stream) {
  (void)in_sizes; (void)n_in; (void)out_size; (void)ws_size;
  const int*   xs  = (const int*)d_in[0];
  const float* emb = (const float*)d_in[1];
  const float* Wq  = (const float*)d_in[2];
  const float* bq  = (const float*)d_in[3];
  const float* Wk  = (const float*)d_in[4];
  const float* bk  = (const float*)d_in[5];
  const float* Wv  = (const float*)d_in[6];
  const float* bv  = (const float*)d_in[7];
  const float* Wo  = (const float*)d_in[8];
  const float* bo  = (const float*)d_in[9];
  const float* att_scale   = (const float*)d_in[10];
  const float* mlp_scale   = (const float*)d_in[11];
  const float* final_scale = (const float*)d_in[12];
  const float* W1  = (const float*)d_in[13];
  const float* A1  = (const float*)d_in[14];
  const float* a1b = (const float*)d_in[15];
  const float* B1  = (const float*)d_in[16];
  const float* b1b = (const float*)d_in[17];
  const float* W2  = (const float*)d_in[18];
  const float* A2  = (const float*)d_in[19];
  const float* a2b = (const float*)d_in[20];
  const float* B2  = (const float*)d_in[21];
  const float* b2b = (const float*)d_in[22];
  const float* W3  = (const float*)d_in[23];
  const float* A3  = (const float*)d_in[24];
  const float* a3b = (const float*)d_in[25];
  const float* B3  = (const float*)d_in[26];
  const float* b3b = (const float*)d_in[27];
  float* out = (float*)d_out;

  // f32 workspace
  float* ws   = (float*)d_ws;
  float* xbuf = ws;
  float* qbuf = xbuf + (size_t)M_ * D_;
  float* kbuf = qbuf + (size_t)M_ * D_;
  float* vbuf = kbuf + (size_t)M_ * KD_;
  float* g1   = vbuf + (size_t)M_ * KD_;
  float* g2   = g1 + (size_t)M_ * HID_;
  float* ubuf = g2 + (size_t)M_ * HID_;
  // bf16 scratch
  ushort_t* hb   = (ushort_t*)(ubuf + (size_t)M_ * R_);   // M*HID ushorts
  ushort_t* wT   = hb + (size_t)M_ * HID_;                // HID*D ushorts
  ushort_t* At   = wT + (size_t)HID_ * D_;                // R*HID ushorts
  ushort_t* embT = (ushort_t*)g2;                         // alias (final only)
  // K/V bf16 alias into g1 (dead during attention phase)
  ushort_t* Kb = (ushort_t*)g1;                           // B*KVH*S*64
  ushort_t* Vt = Kb + (size_t)B_ * KVH_ * S_ * 64;        // B*KVH*64*S

  k_embed<<<dim3(M_ * D_ / 4 / 256), dim3(256), 0, stream>>>(xs, emb, xbuf);

  for (int l = 0; l < L_; ++l) {
    // ---- attention ----
    k_rms<<<dim3(M_), dim3(256), 0, stream>>>(xbuf, att_scale + (size_t)l * D_, hb);
    tcast(stream, Wq + (size_t)l * D_ * D_, wT, D_, D_);
    bgemm(stream, hb, wT, bq + (size_t)l * D_, nullptr, qbuf, M_, D_, D_);
    tcast(stream, Wk + (size_t)l * D_ * KD_, wT, D_, KD_);
    bgemm(stream, hb, wT, bk + (size_t)l * KD_, nullptr, kbuf, M_, KD_, D_);
    tcast(stream, Wv + (size_t)l * D_ * KD_, wT, D_, KD_);
    bgemm(stream, hb, wT, bv + (size_t)l * KD_, nullptr, vbuf, M_, KD_, D_);
    {
      int npq = M_ * QH_ * 32;
      k_rope<<<dim3(npq / 256), dim3(256), 0, stream>>>(qbuf, QH_, npq);
      int npk = M_ * KVH_ * 32;
      k_ropeprep_k<<<dim3(npk / 256), dim3(256), 0, stream>>>(kbuf, Kb);
    }
    k_prep_v<<<dim3(S_ / 32, 2, B_ * KVH_), dim3(256), 0, stream>>>(vbuf, Vt);
    k_attn3<<<dim3(B_ * QH_ * (S_ / 64)), dim3(256), 0, stream>>>(qbuf, Kb, Vt, hb);
    tcast(stream, Wo + (size_t)l * D_ * D_, wT, D_, D_);
    bgemm(stream, hb, wT, bo + (size_t)l * D_, xbuf, xbuf, M_, D_, D_);

    // ---- MLP ----
    k_rms<<<dim3(M_), dim3(256), 0, stream>>>(xbuf, mlp_scale + (size_t)l * D_, hb);
    // lora1: u1 then fused W1-gemm
    k_trA<<<dim3((D_ * R_ + 255) / 256), dim3(256), 0, stream>>>(A1 + (size_t)l * D_ * R_, At, D_);
    k_loraA<D_><<<dim3(M_ / 4), dim3(256), 0, stream>>>(hb, At, a1b + (size_t)l * R_, ubuf);
    tcast(stream, W1 + (size_t)l * D_ * HID_, wT, D_, HID_);
    bgemm_lora(stream, hb, wT, ubuf, B1 + (size_t)l * R_ * HID_, b1b + (size_t)l * HID_,
               nullptr, g1, M_, HID_, D_);
    // lora2
    k_trA<<<dim3((D_ * R_ + 255) / 256), dim3(256), 0, stream>>>(A2 + (size_t)l * D_ * R_, At, D_);
    k_loraA<D_><<<dim3(M_ / 4), dim3(256), 0, stream>>>(hb, At, a2b + (size_t)l * R_, ubuf);
    tcast(stream, W2 + (size_t)l * D_ * HID_, wT, D_, HID_);
    bgemm_lora(stream, hb, wT, ubuf, B2 + (size_t)l * R_ * HID_, b2b + (size_t)l * HID_,
               nullptr, g2, M_, HID_, D_);
    // m = g1 * silu(g2) -> hb (bf16)
    k_silumul<<<dim3(M_ * HID_ / 4 / 256), dim3(256), 0, stream>>>(g1, g2, hb);
    // lora3: x += m@W3 + (u3@B3 + b3b)/32
    k_trA<<<dim3((HID_ * R_ + 255) / 256), dim3(256), 0, stream>>>(A3 + (size_t)l * HID_ * R_, At, HID_);
    k_loraA<HID_><<<dim3(M_ / 4), dim3(256), 0, stream>>>(hb, At, a3b + (size_t)l * R_, ubuf);
    tcast(stream, W3 + (size_t)l * HID_ * D_, wT, HID_, D_);
    bgemm_lora(stream, hb, wT, ubuf, B3 + (size_t)l * R_ * D_, b3b + (size_t)l * D_,
               xbuf, xbuf, M_, D_, HID_);
  }

  // ---- final norm + vocab projection ----
  k_rms<<<dim3(M_), dim3(256), 0, stream>>>(xbuf, final_scale, hb);
  {
    int n8 = (int)((size_t)V_ * D_ / 8);
    k_cast<<<dim3((n8 + 255) / 256), dim3(256), 0, stream>>>(emb, embT, n8);
  }
  bgemm(stream, hb, embT, nullptr, nullptr, out, M_, V_, D_);
}